// Round 6
// baseline (209.816 us; speedup 1.0000x reference)
//
#include <hip/hip_runtime.h>

typedef __attribute__((ext_vector_type(8)))  short bf16x8;
typedef __attribute__((ext_vector_type(16))) float f32x16;
typedef unsigned int u32;
typedef unsigned short u16;

#define HW 6400
#define L2E 1.44269504088896f
#define DEFER_THR 8.0f

__device__ inline u16 f2bf(float f) {
    u32 u = __builtin_bit_cast(u32, f);
    u32 r = (u + 0x7fffu + ((u >> 16) & 1u)) >> 16;
    return (u16)r;
}
__device__ inline u32 cvt_pk_bf16(float lo, float hi) {
    u32 r;
    asm("v_cvt_pk_bf16_f32 %0, %1, %2" : "=v"(r) : "v"(lo), "v"(hi));
    return r;
}
__device__ inline void gload_lds16(const void* g, void* l) {
    __builtin_amdgcn_global_load_lds(
        (const __attribute__((address_space(1))) u32*)g,
        (__attribute__((address_space(3))) u32*)l, 16, 0, 0);
}

// ---------------- Projection kernel (bf16 MFMA — R3/R5-proven, verbatim) ----------------
__global__ __launch_bounds__(256) void proj_kernel(
    const float* __restrict__ x,
    const float* __restrict__ Wq, const float* __restrict__ bq, const float* __restrict__ aq,
    const float* __restrict__ Wk, const float* __restrict__ bk, const float* __restrict__ ak,
    const float* __restrict__ Wv, const float* __restrict__ bv, const float* __restrict__ av,
    u16* __restrict__ QTc, u16* __restrict__ KT, u16* __restrict__ Vw)
{
    __shared__ char xs[64 * 272];      // x tile, [64 p][128 ch bf16 + pad]
    __shared__ char ktr[64 * 144];     // K transpose buffer [64 p][64 ch bf16 + pad]

    const int tid  = threadIdx.x;
    const int lane = tid & 63;
    const int w    = tid >> 6;
    const int l31  = lane & 31;
    const int h    = lane >> 5;

    const int blk = blockIdx.x;
    const int n   = blk / 100;
    const int pt  = blk - n * 100;
    const int p0  = pt * 64;

    const float* xb = x + (size_t)n * 128 * HW + p0;
    #pragma unroll
    for (int it = 0; it < 8; ++it) {
        int idx = it * 256 + tid;
        int c = idx >> 4, p4 = (idx & 15) * 4;
        float4 d = *(const float4*)(xb + (size_t)c * HW + p4);
        *(u16*)(xs + (p4 + 0) * 272 + c * 2) = f2bf(d.x);
        *(u16*)(xs + (p4 + 1) * 272 + c * 2) = f2bf(d.y);
        *(u16*)(xs + (p4 + 2) * 272 + c * 2) = f2bf(d.z);
        *(u16*)(xs + (p4 + 3) * 272 + c * 2) = f2bf(d.w);
    }
    __syncthreads();

    const float* Wsrc; const float* bsrc; float slope; float osc = 1.0f;
    if (w == 0)      { Wsrc = Wq;                 bsrc = bq;             slope = aq[0]; osc = L2E; }
    else if (w == 1) { Wsrc = Wk;                 bsrc = bk;             slope = ak[0]; }
    else             { Wsrc = Wv + (w-2)*64*128;  bsrc = bv + (w-2)*64;  slope = av[0]; }

    bf16x8 wf[2][8];
    #pragma unroll
    for (int cb = 0; cb < 2; ++cb)
        #pragma unroll
        for (int kc = 0; kc < 8; ++kc) {
            const float* ws = Wsrc + (cb * 32 + l31) * 128 + kc * 16 + h * 8;
            float4 a = *(const float4*)ws;
            float4 b = *(const float4*)(ws + 4);
            union { u32 u[4]; bf16x8 v; } uu;
            uu.u[0] = cvt_pk_bf16(a.x, a.y);
            uu.u[1] = cvt_pk_bf16(a.z, a.w);
            uu.u[2] = cvt_pk_bf16(b.x, b.y);
            uu.u[3] = cvt_pk_bf16(b.z, b.w);
            wf[cb][kc] = uu.v;
        }

    f32x16 acc[2][2] = {};
    #pragma unroll
    for (int kc = 0; kc < 8; ++kc) {
        bf16x8 xb0 = *(const bf16x8*)(xs + (l31)      * 272 + kc * 32 + h * 16);
        bf16x8 xb1 = *(const bf16x8*)(xs + (l31 + 32) * 272 + kc * 32 + h * 16);
        acc[0][0] = __builtin_amdgcn_mfma_f32_32x32x16_bf16(wf[0][kc], xb0, acc[0][0], 0, 0, 0);
        acc[0][1] = __builtin_amdgcn_mfma_f32_32x32x16_bf16(wf[0][kc], xb1, acc[0][1], 0, 0, 0);
        acc[1][0] = __builtin_amdgcn_mfma_f32_32x32x16_bf16(wf[1][kc], xb0, acc[1][0], 0, 0, 0);
        acc[1][1] = __builtin_amdgcn_mfma_f32_32x32x16_bf16(wf[1][kc], xb1, acc[1][1], 0, 0, 0);
    }

    if (w != 1) {
        u16* dst = (w == 0) ? (QTc + (size_t)n * 64 * HW)
                            : (Vw + ((size_t)n * 128 + (size_t)(w - 2) * 64) * HW);
        #pragma unroll
        for (int cb = 0; cb < 2; ++cb)
            #pragma unroll
            for (int pb = 0; pb < 2; ++pb)
                #pragma unroll
                for (int r = 0; r < 16; ++r) {
                    int ch = cb * 32 + (r & 3) + 8 * (r >> 2) + 4 * h;
                    float y = acc[cb][pb][r] + bsrc[ch];
                    y = (y >= 0.f) ? y : slope * y;
                    dst[(size_t)ch * HW + p0 + pb * 32 + l31] = f2bf(y * osc);
                }
    } else {
        #pragma unroll
        for (int cb = 0; cb < 2; ++cb)
            #pragma unroll
            for (int pb = 0; pb < 2; ++pb)
                #pragma unroll
                for (int rp = 0; rp < 8; ++rp) {
                    int r0 = rp * 2;
                    int ch = cb * 32 + (r0 & 3) + 8 * (r0 >> 2) + 4 * h;
                    float y0 = acc[cb][pb][r0]     + bsrc[ch];
                    float y1 = acc[cb][pb][r0 + 1] + bsrc[ch + 1];
                    y0 = (y0 >= 0.f) ? y0 : slope * y0;
                    y1 = (y1 >= 0.f) ? y1 : slope * y1;
                    *(u32*)(ktr + (pb * 32 + l31) * 144 + ch * 2) = cvt_pk_bf16(y0, y1);
                }
        #pragma unroll
        for (int i8 = 0; i8 < 8; ++i8) {
            int p = i8 * 8 + (lane >> 3);
            bf16x8 d = *(const bf16x8*)(ktr + p * 144 + (lane & 7) * 16);
            *(bf16x8*)(KT + ((size_t)n * HW + p0 + p) * 64 + (lane & 7) * 8) = d;
        }
    }
}

// ---------------- Flash attention (single-set, 3 waves/SIMD) ----------------
// block 256 = 4 waves x 32 q-rows = 128 rows; grid = 4n x 50 it x jsplit.
// K read directly from global (L2-resident) -> LDS = V double-buffer only (32KB).
// V LDS chunk-major: chunk v (jcc=v>>1, chalf=v&1) at v*1024 + l*16 -> 0 conflicts.
// acc single-set = 64 AGPR; __launch_bounds__(256,3) targets <=170 regs/wave.
__global__ __launch_bounds__(256, 3) void attn_kernel(
    const u16* __restrict__ QTc, const u16* __restrict__ KT, const u16* __restrict__ Vw,
    float* __restrict__ out,
    float* __restrict__ Opart, float* __restrict__ Mpart, float* __restrict__ Lpart,
    int jsplit, int NT)
{
    __shared__ char lds[32768];        // 2 x 16KB V tiles

    const int tid  = threadIdx.x;
    const int lane = tid & 63;
    const int w    = tid >> 6;
    const int l31  = lane & 31;
    const int h    = lane >> 5;

    const int per_n = 50 * jsplit;
    const int n    = blockIdx.x / per_n;
    const int rem  = blockIdx.x - n * per_n;
    const int it   = rem / jsplit;
    const int js   = rem - it * jsplit;
    const int i0   = it * 128;
    const int jt0  = js * NT;

    const int row = i0 + w * 32 + l31;

    // Q B-frags (bf16, c-major): k = kc*16 + h*8 + e
    const u16* qb = QTc + (size_t)n * 64 * HW + row;
    bf16x8 qf[4];
    #pragma unroll
    for (int kc = 0; kc < 4; ++kc) {
        union { u16 s[8]; bf16x8 v; } uu;
        #pragma unroll
        for (int e = 0; e < 8; ++e)
            uu.s[e] = qb[(size_t)(kc * 16 + h * 8 + e) * HW];
        qf[kc] = uu.v;
    }

    const u16* KTn = KT + (size_t)n * HW * 64;                  // [p][64] bf16, 128B rows
    const char* Vg = (const char*)(Vw + (size_t)n * 128 * HW);  // [c][HW] bf16

    auto stage = [&](int buf, int jt) {
        char* B = lds + buf * 16384;
        #pragma unroll
        for (int q = 0; q < 4; ++q) {
            int v = w + 4 * q;
            int jcc = v >> 1, chalf = v & 1;
            gload_lds16(Vg + (size_t)(chalf * 64 + lane) * 12800 + (size_t)jt * 128 + jcc * 16,
                        B + v * 1024);
        }
    };

    f32x16 acc[4] = {};
    float m = -3e38f, ls = 0.f;

    auto compute = [&](int buf, int jt) {
        char* Vlds = lds + buf * 16384;

        #pragma unroll
        for (int jb = 0; jb < 2; ++jb) {
            // K A-frags straight from global: row jt*64+jb*32+l31, chunk (2kc+h)
            const u16* Krow = KTn + (size_t)(jt * 64 + jb * 32 + l31) * 64 + h * 8;
            bf16x8 kf[4];
            #pragma unroll
            for (int kc = 0; kc < 4; ++kc)
                kf[kc] = *(const bf16x8*)(Krow + kc * 16);

            f32x16 s = {};
            #pragma unroll
            for (int kc = 0; kc < 4; ++kc)
                s = __builtin_amdgcn_mfma_f32_32x32x16_bf16(kf[kc], qf[kc], s, 0, 0, 0);

            // defer-max online softmax (lane owns q-row `row`; h-halves hold
            // complementary j's -> xor-32 merge gives full row max)
            float rmx = s[0];
            #pragma unroll
            for (int r = 1; r < 16; ++r) rmx = fmaxf(rmx, s[r]);
            rmx = fmaxf(rmx, __shfl_xor(rmx, 32, 64));

            if (__any(rmx > m + DEFER_THR)) {
                float mn = fmaxf(m, rmx);
                float a = exp2f(m - mn);
                ls *= a;
                #pragma unroll
                for (int cb = 0; cb < 4; ++cb)
                    #pragma unroll
                    for (int r = 0; r < 16; ++r) acc[cb][r] *= a;
                m = mn;
            }

            float rs = 0.f;
            #pragma unroll
            for (int r = 0; r < 16; ++r) { s[r] = exp2f(s[r] - m); rs += s[r]; }
            ls += rs;

            // pack P^T B-frags (bf16) via cvt_pk + permlane32_swap
            bf16x8 pf[2];
            #pragma unroll
            for (int kbl = 0; kbl < 2; ++kbl) {
                const int b = kbl * 8;
                u32 a0 = cvt_pk_bf16(s[b + 0], s[b + 1]);
                u32 a1 = cvt_pk_bf16(s[b + 2], s[b + 3]);
                u32 a2 = cvt_pk_bf16(s[b + 4], s[b + 5]);
                u32 a3 = cvt_pk_bf16(s[b + 6], s[b + 7]);
                asm("v_permlane32_swap_b32 %0, %1" : "+v"(a0), "+v"(a2));
                asm("v_permlane32_swap_b32 %0, %1" : "+v"(a1), "+v"(a3));
                union { u32 u[4]; bf16x8 v; } ua;
                ua.u[0] = a0; ua.u[1] = a1; ua.u[2] = a2; ua.u[3] = a3;
                pf[kbl] = ua.v;
            }

            // O^T += V * P^T
            #pragma unroll
            for (int kbl = 0; kbl < 2; ++kbl) {
                const int jcc = jb * 4 + 2 * kbl + h;
                #pragma unroll
                for (int cb = 0; cb < 4; ++cb) {
                    bf16x8 vf = *(const bf16x8*)(Vlds + jcc * 2048 + (cb * 32 + l31) * 16);
                    acc[cb] = __builtin_amdgcn_mfma_f32_32x32x16_bf16(vf, pf[kbl], acc[cb], 0, 0, 0);
                }
            }
        }
    };

    stage(0, jt0);
    __syncthreads();
    int t = 0;
    for (; t + 2 <= NT; t += 2) {
        stage(1, jt0 + t + 1);
        compute(0, jt0 + t);
        __syncthreads();
        if (t + 2 < NT) stage(0, jt0 + t + 2);
        compute(1, jt0 + t + 1);
        __syncthreads();
    }
    if (t < NT) compute(0, jt0 + t);

    ls += __shfl_xor(ls, 32, 64);

    // epilogue: q = l31 lane-local; c = cb*32+(r&3)+8(r>>2)+4h
    if (Opart != nullptr) {
        float* Ob = Opart + (size_t)(js * 4 + n) * 128 * HW;
        #pragma unroll
        for (int cb = 0; cb < 4; ++cb)
            #pragma unroll
            for (int r = 0; r < 16; ++r) {
                int c = cb * 32 + (r & 3) + 8 * (r >> 2) + 4 * h;
                Ob[(size_t)c * HW + row] = acc[cb][r];
            }
        if (h == 0) {
            Mpart[(size_t)(js * 4 + n) * HW + row] = m;
            Lpart[(size_t)(js * 4 + n) * HW + row] = ls;
        }
    } else {
        float inv = 1.f / ls;
        float* ob = out + (size_t)n * 128 * HW;
        #pragma unroll
        for (int cb = 0; cb < 4; ++cb)
            #pragma unroll
            for (int r = 0; r < 16; ++r) {
                int c = cb * 32 + (r & 3) + 8 * (r >> 2) + 4 * h;
                ob[(size_t)c * HW + row] = acc[cb][r] * inv;
            }
    }
}

// ---------------- Combine (M-aware, jsplit <= 5) ----------------
__global__ __launch_bounds__(256) void combine_kernel(
    const float* __restrict__ Opart, const float* __restrict__ Mpart,
    const float* __restrict__ Lpart, float* __restrict__ out, int jsplit)
{
    const int b = blockIdx.x;
    const int n = b / 100;
    const int rem = b - n * 100;
    const int cq = rem / 25;
    const int ic = rem - cq * 25;
    const int i = ic * 256 + threadIdx.x;

    float mj[5], wj[5];
    float M = -3e38f;
    #pragma unroll
    for (int js = 0; js < 5; ++js) {
        mj[js] = (js < jsplit) ? Mpart[(size_t)(js * 4 + n) * HW + i] : -3e38f;
        M = fmaxf(M, mj[js]);
    }
    float L = 0.f;
    #pragma unroll
    for (int js = 0; js < 5; ++js) {
        wj[js] = (js < jsplit) ? exp2f(mj[js] - M) : 0.f;
        if (js < jsplit) L += Lpart[(size_t)(js * 4 + n) * HW + i] * wj[js];
    }
    const float inv = 1.f / L;

    for (int c = cq * 32; c < cq * 32 + 32; ++c) {
        float acc = 0.f;
        #pragma unroll
        for (int js = 0; js < 5; ++js)
            if (js < jsplit)
                acc += Opart[((size_t)(js * 4 + n) * 128 + c) * HW + i] * wj[js];
        out[((size_t)n * 128 + c) * HW + i] = acc * inv;
    }
}

extern "C" void kernel_launch(void* const* d_in, const int* in_sizes, int n_in,
                              void* d_out, int out_size, void* d_ws, size_t ws_size,
                              hipStream_t stream) {
    const float* x  = (const float*)d_in[0];
    const float* Wq = (const float*)d_in[1];
    const float* bq = (const float*)d_in[2];
    const float* aq = (const float*)d_in[3];
    const float* Wk = (const float*)d_in[4];
    const float* bk = (const float*)d_in[5];
    const float* ak = (const float*)d_in[6];
    const float* Wv = (const float*)d_in[7];
    const float* bv = (const float*)d_in[8];
    const float* av = (const float*)d_in[9];

    char* wsp = (char*)d_ws;
    u16* QTc = (u16*)wsp;                          // [4][64][6400] bf16  = 3,276,800 B
    u16* KT  = (u16*)(wsp + 3276800);              // [4][6400][64] bf16  = 3,276,800 B
    u16* Vw  = (u16*)(wsp + 6553600);              // [4][128][6400] bf16 = 6,553,600 B
    const size_t base = 13107200;
    const size_t oslab = 13107200;                 // 128*6400*4 B per (js,n=4) slab
    const size_t mslab = 102400;                   // 4*6400*4 B

    proj_kernel<<<dim3(400), 256, 0, stream>>>(x, Wq, bq, aq, Wk, bk, ak, Wv, bv, av,
                                               QTc, KT, Vw);

    int jsplit = 0;
    for (int js = 5; js >= 4; --js) {
        size_t need = base + (size_t)js * (oslab + 2 * mslab);
        if (ws_size >= need) { jsplit = js; break; }
    }

    if (jsplit > 0) {
        float* Opart = (float*)(wsp + base);
        float* Mpart = (float*)(wsp + base + (size_t)jsplit * oslab);
        float* Lpart = (float*)(wsp + base + (size_t)jsplit * (oslab + mslab));
        int NT = 100 / jsplit;
        attn_kernel<<<dim3(4 * 50 * jsplit), 256, 0, stream>>>(QTc, KT, Vw, (float*)d_out,
                                                               Opart, Mpart, Lpart, jsplit, NT);
        combine_kernel<<<dim3(400), 256, 0, stream>>>(Opart, Mpart, Lpart, (float*)d_out, jsplit);
    } else {
        attn_kernel<<<dim3(200), 256, 0, stream>>>(QTc, KT, Vw, (float*)d_out,
                                                   nullptr, nullptr, nullptr, 1, 100);
    }
}

// Round 7
// 208.699 us; speedup vs baseline: 1.0054x; 1.0054x over previous
//
#include <hip/hip_runtime.h>

typedef __attribute__((ext_vector_type(8)))  short bf16x8;
typedef __attribute__((ext_vector_type(16))) float f32x16;
typedef unsigned int u32;
typedef unsigned short u16;

#define HW 6400
#define L2E 1.44269504088896f
#define DEFER_THR 8.0f

__device__ inline u16 f2bf(float f) {
    u32 u = __builtin_bit_cast(u32, f);
    u32 r = (u + 0x7fffu + ((u >> 16) & 1u)) >> 16;
    return (u16)r;
}
__device__ inline u32 cvt_pk_bf16(float lo, float hi) {
    u32 r;
    asm("v_cvt_pk_bf16_f32 %0, %1, %2" : "=v"(r) : "v"(lo), "v"(hi));
    return r;
}

// ---------------- Projection kernel (bf16 MFMA) ----------------
// grid 400 = 4n x 100 p-tiles of 64, block 256 = 4 waves.
// wave 0 -> Q (x log2e, p-major via LDS transpose), wave 1 -> K (p-major via
// LDS transpose), waves 2/3 -> V[0:64]/V[64:128] (bf16 c-major).
__global__ __launch_bounds__(256) void proj_kernel(
    const float* __restrict__ x,
    const float* __restrict__ Wq, const float* __restrict__ bq, const float* __restrict__ aq,
    const float* __restrict__ Wk, const float* __restrict__ bk, const float* __restrict__ ak,
    const float* __restrict__ Wv, const float* __restrict__ bv, const float* __restrict__ av,
    u16* __restrict__ QT, u16* __restrict__ KT, u16* __restrict__ Vw)
{
    __shared__ char xs[64 * 272];      // x tile, [64 p][128 ch bf16 + pad]
    __shared__ char ktr[2][64 * 144];  // Q/K transpose buffers [64 p][64 ch + pad]

    const int tid  = threadIdx.x;
    const int lane = tid & 63;
    const int w    = tid >> 6;
    const int l31  = lane & 31;
    const int h    = lane >> 5;

    const int blk = blockIdx.x;
    const int n   = blk / 100;
    const int pt  = blk - n * 100;
    const int p0  = pt * 64;

    const float* xb = x + (size_t)n * 128 * HW + p0;
    #pragma unroll
    for (int it = 0; it < 8; ++it) {
        int idx = it * 256 + tid;
        int c = idx >> 4, p4 = (idx & 15) * 4;
        float4 d = *(const float4*)(xb + (size_t)c * HW + p4);
        *(u16*)(xs + (p4 + 0) * 272 + c * 2) = f2bf(d.x);
        *(u16*)(xs + (p4 + 1) * 272 + c * 2) = f2bf(d.y);
        *(u16*)(xs + (p4 + 2) * 272 + c * 2) = f2bf(d.z);
        *(u16*)(xs + (p4 + 3) * 272 + c * 2) = f2bf(d.w);
    }
    __syncthreads();

    const float* Wsrc; const float* bsrc; float slope; float osc = 1.0f;
    if (w == 0)      { Wsrc = Wq;                 bsrc = bq;             slope = aq[0]; osc = L2E; }
    else if (w == 1) { Wsrc = Wk;                 bsrc = bk;             slope = ak[0]; }
    else             { Wsrc = Wv + (w-2)*64*128;  bsrc = bv + (w-2)*64;  slope = av[0]; }

    bf16x8 wf[2][8];
    #pragma unroll
    for (int cb = 0; cb < 2; ++cb)
        #pragma unroll
        for (int kc = 0; kc < 8; ++kc) {
            const float* ws = Wsrc + (cb * 32 + l31) * 128 + kc * 16 + h * 8;
            float4 a = *(const float4*)ws;
            float4 b = *(const float4*)(ws + 4);
            union { u32 u[4]; bf16x8 v; } uu;
            uu.u[0] = cvt_pk_bf16(a.x, a.y);
            uu.u[1] = cvt_pk_bf16(a.z, a.w);
            uu.u[2] = cvt_pk_bf16(b.x, b.y);
            uu.u[3] = cvt_pk_bf16(b.z, b.w);
            wf[cb][kc] = uu.v;
        }

    f32x16 acc[2][2] = {};
    #pragma unroll
    for (int kc = 0; kc < 8; ++kc) {
        bf16x8 xb0 = *(const bf16x8*)(xs + (l31)      * 272 + kc * 32 + h * 16);
        bf16x8 xb1 = *(const bf16x8*)(xs + (l31 + 32) * 272 + kc * 32 + h * 16);
        acc[0][0] = __builtin_amdgcn_mfma_f32_32x32x16_bf16(wf[0][kc], xb0, acc[0][0], 0, 0, 0);
        acc[0][1] = __builtin_amdgcn_mfma_f32_32x32x16_bf16(wf[0][kc], xb1, acc[0][1], 0, 0, 0);
        acc[1][0] = __builtin_amdgcn_mfma_f32_32x32x16_bf16(wf[1][kc], xb0, acc[1][0], 0, 0, 0);
        acc[1][1] = __builtin_amdgcn_mfma_f32_32x32x16_bf16(wf[1][kc], xb1, acc[1][1], 0, 0, 0);
    }

    // D: col p = l31 + pb*32, row ch = cb*32 + (r&3)+8*(r>>2)+4h
    if (w >= 2) {
        u16* dst = Vw + ((size_t)n * 128 + (size_t)(w - 2) * 64) * HW;
        #pragma unroll
        for (int cb = 0; cb < 2; ++cb)
            #pragma unroll
            for (int pb = 0; pb < 2; ++pb)
                #pragma unroll
                for (int r = 0; r < 16; ++r) {
                    int ch = cb * 32 + (r & 3) + 8 * (r >> 2) + 4 * h;
                    float y = acc[cb][pb][r] + bsrc[ch];
                    y = (y >= 0.f) ? y : slope * y;
                    dst[(size_t)ch * HW + p0 + pb * 32 + l31] = f2bf(y);
                }
    } else {
        // Q/K: bias+PReLU (+osc), pack ch-pairs, transpose through LDS, store p-major
        char* tb = ktr[w];
        #pragma unroll
        for (int cb = 0; cb < 2; ++cb)
            #pragma unroll
            for (int pb = 0; pb < 2; ++pb)
                #pragma unroll
                for (int rp = 0; rp < 8; ++rp) {
                    int r0 = rp * 2;
                    int ch = cb * 32 + (r0 & 3) + 8 * (r0 >> 2) + 4 * h;
                    float y0 = acc[cb][pb][r0]     + bsrc[ch];
                    float y1 = acc[cb][pb][r0 + 1] + bsrc[ch + 1];
                    y0 = ((y0 >= 0.f) ? y0 : slope * y0) * osc;
                    y1 = ((y1 >= 0.f) ? y1 : slope * y1) * osc;
                    *(u32*)(tb + (pb * 32 + l31) * 144 + ch * 2) = cvt_pk_bf16(y0, y1);
                }
        u16* dst = (w == 0) ? QT : KT;
        #pragma unroll
        for (int i8 = 0; i8 < 8; ++i8) {
            int p = i8 * 8 + (lane >> 3);
            bf16x8 d = *(const bf16x8*)(tb + p * 144 + (lane & 7) * 16);
            *(bf16x8*)(dst + ((size_t)n * HW + p0 + p) * 64 + (lane & 7) * 8) = d;
        }
    }
}

// ---------------- Flash attention (no LDS, no barriers, L2-direct) ----------------
// block 128 = 2 waves x 64 q-rows (dual-set A/B) = 128 rows; grid = 8-divisible.
// XCD-clustered bid mapping keeps each (n,js) K/V slice (~0.5MB) on ~one XCD's L2.
// All K/V fragment reads go straight to L2 with the same per-lane addresses the
// R5 LDS mirror held -> outputs bit-identical to R5.
__global__ __launch_bounds__(128, 2) void attn_kernel(
    const u16* __restrict__ QT, const u16* __restrict__ KT, const u16* __restrict__ Vw,
    float* __restrict__ out,
    float* __restrict__ Opart, float* __restrict__ Mpart, float* __restrict__ Lpart,
    int jsplit, int NT)
{
    const int tid  = threadIdx.x;
    const int lane = tid & 63;
    const int w    = tid >> 6;       // 0..1
    const int l31  = lane & 31;
    const int h    = lane >> 5;

    // XCD-clustered mapping (grid divisible by 8): consecutive `linear` share (n,js)
    const int perx   = gridDim.x >> 3;
    const int linear = (blockIdx.x & 7) * perx + (blockIdx.x >> 3);
    const int g      = linear / 50;          // (n,js) group
    const int itl    = linear - g * 50;
    const int n      = g / jsplit;
    const int js     = g - n * jsplit;
    const int i0     = itl * 128;
    const int jt0    = js * NT;

    const int rowA = i0 + w * 64 + l31;
    const int rowB = rowA + 32;

    // Q B-frags from p-major QT: 4 x b128 per set
    const u16* qbA = QT + ((size_t)n * HW + rowA) * 64;
    bf16x8 qfA[4], qfB[4];
    #pragma unroll
    for (int kc = 0; kc < 4; ++kc) {
        qfA[kc] = *(const bf16x8*)(qbA + kc * 16 + h * 8);
        qfB[kc] = *(const bf16x8*)(qbA + 32 * 64 + kc * 16 + h * 8);
    }

    const u16* KTn = KT + (size_t)n * HW * 64;    // [p][64] bf16, 128B rows
    const u16* Vn  = Vw + (size_t)n * 128 * HW;   // [c][HW] bf16

    f32x16 accA[4] = {}, accB[4] = {};
    float mA = -3e38f, mB = -3e38f, lsA = 0.f, lsB = 0.f;

    for (int t = 0; t < NT; ++t) {
        const int jt = jt0 + t;
        #pragma unroll
        for (int jb = 0; jb < 2; ++jb) {
            // K A-frags from L2: row jt*64+jb*32+l31, ch-chunk (2kc+h)*8
            const u16* Krow = KTn + (size_t)(jt * 64 + jb * 32 + l31) * 64 + h * 8;
            bf16x8 kf[4];
            #pragma unroll
            for (int kc = 0; kc < 4; ++kc)
                kf[kc] = *(const bf16x8*)(Krow + kc * 16);

            __builtin_amdgcn_s_setprio(1);
            f32x16 sA = {}, sB = {};
            #pragma unroll
            for (int kc = 0; kc < 4; ++kc) {
                sA = __builtin_amdgcn_mfma_f32_32x32x16_bf16(kf[kc], qfA[kc], sA, 0, 0, 0);
                sB = __builtin_amdgcn_mfma_f32_32x32x16_bf16(kf[kc], qfB[kc], sB, 0, 0, 0);
            }
            __builtin_amdgcn_s_setprio(0);

            // defer-max online softmax (identical to R5)
            float rmxA = sA[0], rmxB = sB[0];
            #pragma unroll
            for (int r = 1; r < 16; ++r) {
                rmxA = fmaxf(rmxA, sA[r]);
                rmxB = fmaxf(rmxB, sB[r]);
            }
            rmxA = fmaxf(rmxA, __shfl_xor(rmxA, 32, 64));
            rmxB = fmaxf(rmxB, __shfl_xor(rmxB, 32, 64));

            if (__any(rmxA > mA + DEFER_THR) || __any(rmxB > mB + DEFER_THR)) {
                float mnA = fmaxf(mA, rmxA), mnB = fmaxf(mB, rmxB);
                float aA = exp2f(mA - mnA), aB = exp2f(mB - mnB);
                lsA *= aA; lsB *= aB;
                #pragma unroll
                for (int cb = 0; cb < 4; ++cb)
                    #pragma unroll
                    for (int r = 0; r < 16; ++r) {
                        accA[cb][r] *= aA;
                        accB[cb][r] *= aB;
                    }
                mA = mnA; mB = mnB;
            }

            float rsA = 0.f, rsB = 0.f;
            #pragma unroll
            for (int r = 0; r < 16; ++r) {
                sA[r] = exp2f(sA[r] - mA); rsA += sA[r];
                sB[r] = exp2f(sB[r] - mB); rsB += sB[r];
            }
            lsA += rsA; lsB += rsB;

            // pack P^T B-frags (identical to R5)
            bf16x8 pfA[2], pfB[2];
            #pragma unroll
            for (int kbl = 0; kbl < 2; ++kbl) {
                const int b = kbl * 8;
                u32 a0 = cvt_pk_bf16(sA[b + 0], sA[b + 1]);
                u32 a1 = cvt_pk_bf16(sA[b + 2], sA[b + 3]);
                u32 a2 = cvt_pk_bf16(sA[b + 4], sA[b + 5]);
                u32 a3 = cvt_pk_bf16(sA[b + 6], sA[b + 7]);
                asm("v_permlane32_swap_b32 %0, %1" : "+v"(a0), "+v"(a2));
                asm("v_permlane32_swap_b32 %0, %1" : "+v"(a1), "+v"(a3));
                union { u32 u[4]; bf16x8 v; } ua;
                ua.u[0] = a0; ua.u[1] = a1; ua.u[2] = a2; ua.u[3] = a3;
                pfA[kbl] = ua.v;
                u32 b0 = cvt_pk_bf16(sB[b + 0], sB[b + 1]);
                u32 b1 = cvt_pk_bf16(sB[b + 2], sB[b + 3]);
                u32 b2 = cvt_pk_bf16(sB[b + 4], sB[b + 5]);
                u32 b3 = cvt_pk_bf16(sB[b + 6], sB[b + 7]);
                asm("v_permlane32_swap_b32 %0, %1" : "+v"(b0), "+v"(b2));
                asm("v_permlane32_swap_b32 %0, %1" : "+v"(b1), "+v"(b3));
                union { u32 u[4]; bf16x8 v; } ub;
                ub.u[0] = b0; ub.u[1] = b1; ub.u[2] = b2; ub.u[3] = b3;
                pfB[kbl] = ub.v;
            }

            // O^T += V * P^T ; V frags straight from L2 (vf shared by both sets)
            __builtin_amdgcn_s_setprio(1);
            #pragma unroll
            for (int kbl = 0; kbl < 2; ++kbl) {
                const int jcc = jb * 4 + 2 * kbl + h;
                const u16* Vcol = Vn + (size_t)jt * 64 + jcc * 8;
                #pragma unroll
                for (int cb = 0; cb < 4; ++cb) {
                    bf16x8 vf = *(const bf16x8*)(Vcol + (size_t)(cb * 32 + l31) * HW);
                    accA[cb] = __builtin_amdgcn_mfma_f32_32x32x16_bf16(vf, pfA[kbl], accA[cb], 0, 0, 0);
                    accB[cb] = __builtin_amdgcn_mfma_f32_32x32x16_bf16(vf, pfB[kbl], accB[cb], 0, 0, 0);
                }
            }
            __builtin_amdgcn_s_setprio(0);
        }
    }

    lsA += __shfl_xor(lsA, 32, 64);
    lsB += __shfl_xor(lsB, 32, 64);

    // epilogue (identical to R5): q = l31 lane-local; c = cb*32+(r&3)+8(r>>2)+4h
    if (Opart != nullptr) {
        float* Ob = Opart + (size_t)(js * 4 + n) * 128 * HW;
        #pragma unroll
        for (int cb = 0; cb < 4; ++cb)
            #pragma unroll
            for (int r = 0; r < 16; ++r) {
                int c = cb * 32 + (r & 3) + 8 * (r >> 2) + 4 * h;
                Ob[(size_t)c * HW + rowA] = accA[cb][r];
                Ob[(size_t)c * HW + rowB] = accB[cb][r];
            }
        if (h == 0) {
            Mpart[(size_t)(js * 4 + n) * HW + rowA] = mA;
            Mpart[(size_t)(js * 4 + n) * HW + rowB] = mB;
            Lpart[(size_t)(js * 4 + n) * HW + rowA] = lsA;
            Lpart[(size_t)(js * 4 + n) * HW + rowB] = lsB;
        }
    } else {
        float invA = 1.f / lsA, invB = 1.f / lsB;
        float* ob = out + (size_t)n * 128 * HW;
        #pragma unroll
        for (int cb = 0; cb < 4; ++cb)
            #pragma unroll
            for (int r = 0; r < 16; ++r) {
                int c = cb * 32 + (r & 3) + 8 * (r >> 2) + 4 * h;
                ob[(size_t)c * HW + rowA] = accA[cb][r] * invA;
                ob[(size_t)c * HW + rowB] = accB[cb][r] * invB;
            }
    }
}

// ---------------- Combine (M-aware, jsplit <= 5) ----------------
__global__ __launch_bounds__(256) void combine_kernel(
    const float* __restrict__ Opart, const float* __restrict__ Mpart,
    const float* __restrict__ Lpart, float* __restrict__ out, int jsplit)
{
    const int b = blockIdx.x;
    const int n = b / 100;
    const int rem = b - n * 100;
    const int cq = rem / 25;
    const int ic = rem - cq * 25;
    const int i = ic * 256 + threadIdx.x;

    float mj[5], wj[5];
    float M = -3e38f;
    #pragma unroll
    for (int js = 0; js < 5; ++js) {
        mj[js] = (js < jsplit) ? Mpart[(size_t)(js * 4 + n) * HW + i] : -3e38f;
        M = fmaxf(M, mj[js]);
    }
    float L = 0.f;
    #pragma unroll
    for (int js = 0; js < 5; ++js) {
        wj[js] = (js < jsplit) ? exp2f(mj[js] - M) : 0.f;
        if (js < jsplit) L += Lpart[(size_t)(js * 4 + n) * HW + i] * wj[js];
    }
    const float inv = 1.f / L;

    for (int c = cq * 32; c < cq * 32 + 32; ++c) {
        float acc = 0.f;
        #pragma unroll
        for (int js = 0; js < 5; ++js)
            if (js < jsplit)
                acc += Opart[((size_t)(js * 4 + n) * 128 + c) * HW + i] * wj[js];
        out[((size_t)n * 128 + c) * HW + i] = acc * inv;
    }
}

extern "C" void kernel_launch(void* const* d_in, const int* in_sizes, int n_in,
                              void* d_out, int out_size, void* d_ws, size_t ws_size,
                              hipStream_t stream) {
    const float* x  = (const float*)d_in[0];
    const float* Wq = (const float*)d_in[1];
    const float* bq = (const float*)d_in[2];
    const float* aq = (const float*)d_in[3];
    const float* Wk = (const float*)d_in[4];
    const float* bk = (const float*)d_in[5];
    const float* ak = (const float*)d_in[6];
    const float* Wv = (const float*)d_in[7];
    const float* bv = (const float*)d_in[8];
    const float* av = (const float*)d_in[9];

    char* wsp = (char*)d_ws;
    u16* QT  = (u16*)wsp;                          // [4][6400][64] bf16 p-major = 3,276,800 B
    u16* KT  = (u16*)(wsp + 3276800);              // [4][6400][64] bf16 p-major = 3,276,800 B
    u16* Vw  = (u16*)(wsp + 6553600);              // [4][128][6400] bf16 c-major = 6,553,600 B
    const size_t base = 13107200;
    const size_t oslab = 13107200;                 // 4n x 128 x HW x 4B per js
    const size_t mslab = 102400;                   // 4n x HW x 4B

    proj_kernel<<<dim3(400), 256, 0, stream>>>(x, Wq, bq, aq, Wk, bk, ak, Wv, bv, av,
                                               QT, KT, Vw);

    int jsplit = 0;
    for (int js = 5; js >= 4; --js) {
        size_t need = base + (size_t)js * (oslab + 2 * mslab);
        if (ws_size >= need) { jsplit = js; break; }
    }

    if (jsplit > 0) {
        float* Opart = (float*)(wsp + base);
        float* Mpart = (float*)(wsp + base + (size_t)jsplit * oslab);
        float* Lpart = (float*)(wsp + base + (size_t)jsplit * (oslab + mslab));
        int NT = 100 / jsplit;
        // grid = 4n x 50 it x jsplit; divisible by 8 for jsplit 4 or 5 (800/1000)
        attn_kernel<<<dim3(4 * 50 * jsplit), 128, 0, stream>>>(QT, KT, Vw, (float*)d_out,
                                                               Opart, Mpart, Lpart, jsplit, NT);
        combine_kernel<<<dim3(400), 256, 0, stream>>>(Opart, Mpart, Lpart, (float*)d_out, jsplit);
    } else {
        // fallback: jsplit=1, grid 200 (divisible by 8), full j-range per block
        attn_kernel<<<dim3(200), 128, 0, stream>>>(QT, KT, Vw, (float*)d_out,
                                                   nullptr, nullptr, nullptr, 1, 100);
    }
}

// Round 8
// 181.652 us; speedup vs baseline: 1.1550x; 1.1489x over previous
//
#include <hip/hip_runtime.h>

typedef __attribute__((ext_vector_type(8)))  short bf16x8;
typedef __attribute__((ext_vector_type(16))) float f32x16;
typedef unsigned int u32;
typedef unsigned short u16;

#define HW 6400
#define L2E 1.44269504088896f
#define DEFER_THR 8.0f

__device__ inline u16 f2bf(float f) {
    u32 u = __builtin_bit_cast(u32, f);
    u32 r = (u + 0x7fffu + ((u >> 16) & 1u)) >> 16;
    return (u16)r;
}
__device__ inline u32 cvt_pk_bf16(float lo, float hi) {
    u32 r;
    asm("v_cvt_pk_bf16_f32 %0, %1, %2" : "=v"(r) : "v"(lo), "v"(hi));
    return r;
}
__device__ inline void gload_lds16(const void* g, void* l) {
    __builtin_amdgcn_global_load_lds(
        (const __attribute__((address_space(1))) u32*)g,
        (__attribute__((address_space(3))) u32*)l, 16, 0, 0);
}

// ---------------- Projection kernel (bf16 MFMA — R7-proven, verbatim) ----------------
// wave 0 -> Q (x log2e, p-major via LDS transpose), wave 1 -> K (p-major via
// LDS transpose), waves 2/3 -> V[0:64]/V[64:128] (bf16 c-major).
__global__ __launch_bounds__(256) void proj_kernel(
    const float* __restrict__ x,
    const float* __restrict__ Wq, const float* __restrict__ bq, const float* __restrict__ aq,
    const float* __restrict__ Wk, const float* __restrict__ bk, const float* __restrict__ ak,
    const float* __restrict__ Wv, const float* __restrict__ bv, const float* __restrict__ av,
    u16* __restrict__ QT, u16* __restrict__ KT, u16* __restrict__ Vw)
{
    __shared__ char xs[64 * 272];
    __shared__ char ktr[2][64 * 144];

    const int tid  = threadIdx.x;
    const int lane = tid & 63;
    const int w    = tid >> 6;
    const int l31  = lane & 31;
    const int h    = lane >> 5;

    const int blk = blockIdx.x;
    const int n   = blk / 100;
    const int pt  = blk - n * 100;
    const int p0  = pt * 64;

    const float* xb = x + (size_t)n * 128 * HW + p0;
    #pragma unroll
    for (int it = 0; it < 8; ++it) {
        int idx = it * 256 + tid;
        int c = idx >> 4, p4 = (idx & 15) * 4;
        float4 d = *(const float4*)(xb + (size_t)c * HW + p4);
        *(u16*)(xs + (p4 + 0) * 272 + c * 2) = f2bf(d.x);
        *(u16*)(xs + (p4 + 1) * 272 + c * 2) = f2bf(d.y);
        *(u16*)(xs + (p4 + 2) * 272 + c * 2) = f2bf(d.z);
        *(u16*)(xs + (p4 + 3) * 272 + c * 2) = f2bf(d.w);
    }
    __syncthreads();

    const float* Wsrc; const float* bsrc; float slope; float osc = 1.0f;
    if (w == 0)      { Wsrc = Wq;                 bsrc = bq;             slope = aq[0]; osc = L2E; }
    else if (w == 1) { Wsrc = Wk;                 bsrc = bk;             slope = ak[0]; }
    else             { Wsrc = Wv + (w-2)*64*128;  bsrc = bv + (w-2)*64;  slope = av[0]; }

    bf16x8 wf[2][8];
    #pragma unroll
    for (int cb = 0; cb < 2; ++cb)
        #pragma unroll
        for (int kc = 0; kc < 8; ++kc) {
            const float* ws = Wsrc + (cb * 32 + l31) * 128 + kc * 16 + h * 8;
            float4 a = *(const float4*)ws;
            float4 b = *(const float4*)(ws + 4);
            union { u32 u[4]; bf16x8 v; } uu;
            uu.u[0] = cvt_pk_bf16(a.x, a.y);
            uu.u[1] = cvt_pk_bf16(a.z, a.w);
            uu.u[2] = cvt_pk_bf16(b.x, b.y);
            uu.u[3] = cvt_pk_bf16(b.z, b.w);
            wf[cb][kc] = uu.v;
        }

    f32x16 acc[2][2] = {};
    #pragma unroll
    for (int kc = 0; kc < 8; ++kc) {
        bf16x8 xb0 = *(const bf16x8*)(xs + (l31)      * 272 + kc * 32 + h * 16);
        bf16x8 xb1 = *(const bf16x8*)(xs + (l31 + 32) * 272 + kc * 32 + h * 16);
        acc[0][0] = __builtin_amdgcn_mfma_f32_32x32x16_bf16(wf[0][kc], xb0, acc[0][0], 0, 0, 0);
        acc[0][1] = __builtin_amdgcn_mfma_f32_32x32x16_bf16(wf[0][kc], xb1, acc[0][1], 0, 0, 0);
        acc[1][0] = __builtin_amdgcn_mfma_f32_32x32x16_bf16(wf[1][kc], xb0, acc[1][0], 0, 0, 0);
        acc[1][1] = __builtin_amdgcn_mfma_f32_32x32x16_bf16(wf[1][kc], xb1, acc[1][1], 0, 0, 0);
    }

    if (w >= 2) {
        u16* dst = Vw + ((size_t)n * 128 + (size_t)(w - 2) * 64) * HW;
        #pragma unroll
        for (int cb = 0; cb < 2; ++cb)
            #pragma unroll
            for (int pb = 0; pb < 2; ++pb)
                #pragma unroll
                for (int r = 0; r < 16; ++r) {
                    int ch = cb * 32 + (r & 3) + 8 * (r >> 2) + 4 * h;
                    float y = acc[cb][pb][r] + bsrc[ch];
                    y = (y >= 0.f) ? y : slope * y;
                    dst[(size_t)ch * HW + p0 + pb * 32 + l31] = f2bf(y);
                }
    } else {
        char* tb = ktr[w];
        #pragma unroll
        for (int cb = 0; cb < 2; ++cb)
            #pragma unroll
            for (int pb = 0; pb < 2; ++pb)
                #pragma unroll
                for (int rp = 0; rp < 8; ++rp) {
                    int r0 = rp * 2;
                    int ch = cb * 32 + (r0 & 3) + 8 * (r0 >> 2) + 4 * h;
                    float y0 = acc[cb][pb][r0]     + bsrc[ch];
                    float y1 = acc[cb][pb][r0 + 1] + bsrc[ch + 1];
                    y0 = ((y0 >= 0.f) ? y0 : slope * y0) * osc;
                    y1 = ((y1 >= 0.f) ? y1 : slope * y1) * osc;
                    *(u32*)(tb + (pb * 32 + l31) * 144 + ch * 2) = cvt_pk_bf16(y0, y1);
                }
        u16* dst = (w == 0) ? QT : KT;
        #pragma unroll
        for (int i8 = 0; i8 < 8; ++i8) {
            int p = i8 * 8 + (lane >> 3);
            bf16x8 d = *(const bf16x8*)(tb + p * 144 + (lane & 7) * 16);
            *(bf16x8*)(dst + ((size_t)n * HW + p0 + p) * 64 + (lane & 7) * 8) = d;
        }
    }
}

// ---------------- Flash attention (R5 structure + T4 counted vmcnt + T5) ----------------
// block 256 = 4 waves x 64 q-rows (dual-set A/B) = 256 rows; grid = 4n x 25 it x jsplit.
// Double-buffered 24KB K/V tiles via global_load_lds (6 loads/wave/tile).
// Counted s_waitcnt vmcnt(6): next tile's loads stay in flight across barriers;
// raw s_barrier (no drain) + sched_barrier(0) fences per rule #18.
__global__ __launch_bounds__(256, 2) void attn_kernel(
    const u16* __restrict__ QT, const u16* __restrict__ KT, const u16* __restrict__ Vw,
    float* __restrict__ out,
    float* __restrict__ Opart, float* __restrict__ Mpart, float* __restrict__ Lpart,
    int jsplit, int NT)
{
    __shared__ char lds[49152];        // 2 x (K 8KB + V 16KB)

    const int tid  = threadIdx.x;
    const int lane = tid & 63;
    const int w    = tid >> 6;
    const int l31  = lane & 31;
    const int h    = lane >> 5;

    const int per_n = 25 * jsplit;
    const int n    = blockIdx.x / per_n;
    const int rem  = blockIdx.x - n * per_n;
    const int it   = rem / jsplit;
    const int js   = rem - it * jsplit;
    const int i0   = it * 256;
    const int jt0  = js * NT;

    const int rowA = i0 + w * 64 + l31;
    const int rowB = rowA + 32;

    // Q B-frags from p-major QT: 4 x b128 per set (values identical to R5's)
    const u16* qbA = QT + ((size_t)n * HW + rowA) * 64;
    bf16x8 qfA[4], qfB[4];
    #pragma unroll
    for (int kc = 0; kc < 4; ++kc) {
        qfA[kc] = *(const bf16x8*)(qbA + kc * 16 + h * 8);
        qfB[kc] = *(const bf16x8*)(qbA + 32 * 64 + kc * 16 + h * 8);
    }

    const char* Kg = (const char*)(KT + (size_t)n * HW * 64);    // [p][64] bf16, 128B rows
    const char* Vg = (const char*)(Vw + (size_t)n * 128 * HW);   // [c][HW] bf16

    // 6 global_load_lds per wave per tile (2 K + 4 V), chunk-major LDS layout
    auto stage = [&](int buf, int jt) {
        char* B = lds + buf * 24576;
        #pragma unroll
        for (int q = 0; q < 2; ++q) {
            int cc = w + 4 * q;
            gload_lds16(Kg + (size_t)jt * 8192 + lane * 128 + cc * 16, B + cc * 1024);
        }
        #pragma unroll
        for (int q = 0; q < 4; ++q) {
            int v = w + 4 * q;
            int jcc = v >> 1, chalf = v & 1;
            gload_lds16(Vg + (size_t)(chalf * 64 + lane) * 12800 + (size_t)jt * 128 + jcc * 16,
                        B + 8192 + v * 1024);
        }
    };

    f32x16 accA[4] = {}, accB[4] = {};
    float mA = -3e38f, mB = -3e38f, lsA = 0.f, lsB = 0.f;

    auto compute = [&](int buf) {
        char* Klds = lds + buf * 24576;
        char* Vlds = Klds + 8192;

        #pragma unroll
        for (int jb = 0; jb < 2; ++jb) {
            bf16x8 kf[4];
            #pragma unroll
            for (int kc = 0; kc < 4; ++kc)
                kf[kc] = *(const bf16x8*)(Klds + (2 * kc + h) * 1024 + (jb * 32 + l31) * 16);

            __builtin_amdgcn_s_setprio(1);
            f32x16 sA = {}, sB = {};
            #pragma unroll
            for (int kc = 0; kc < 4; ++kc) {
                sA = __builtin_amdgcn_mfma_f32_32x32x16_bf16(kf[kc], qfA[kc], sA, 0, 0, 0);
                sB = __builtin_amdgcn_mfma_f32_32x32x16_bf16(kf[kc], qfB[kc], sB, 0, 0, 0);
            }
            __builtin_amdgcn_s_setprio(0);

            float rmxA = sA[0], rmxB = sB[0];
            #pragma unroll
            for (int r = 1; r < 16; ++r) {
                rmxA = fmaxf(rmxA, sA[r]);
                rmxB = fmaxf(rmxB, sB[r]);
            }
            rmxA = fmaxf(rmxA, __shfl_xor(rmxA, 32, 64));
            rmxB = fmaxf(rmxB, __shfl_xor(rmxB, 32, 64));

            if (__any(rmxA > mA + DEFER_THR) || __any(rmxB > mB + DEFER_THR)) {
                float mnA = fmaxf(mA, rmxA), mnB = fmaxf(mB, rmxB);
                float aA = exp2f(mA - mnA), aB = exp2f(mB - mnB);
                lsA *= aA; lsB *= aB;
                #pragma unroll
                for (int cb = 0; cb < 4; ++cb)
                    #pragma unroll
                    for (int r = 0; r < 16; ++r) {
                        accA[cb][r] *= aA;
                        accB[cb][r] *= aB;
                    }
                mA = mnA; mB = mnB;
            }

            float rsA = 0.f, rsB = 0.f;
            #pragma unroll
            for (int r = 0; r < 16; ++r) {
                sA[r] = exp2f(sA[r] - mA); rsA += sA[r];
                sB[r] = exp2f(sB[r] - mB); rsB += sB[r];
            }
            lsA += rsA; lsB += rsB;

            bf16x8 pfA[2], pfB[2];
            #pragma unroll
            for (int kbl = 0; kbl < 2; ++kbl) {
                const int b = kbl * 8;
                u32 a0 = cvt_pk_bf16(sA[b + 0], sA[b + 1]);
                u32 a1 = cvt_pk_bf16(sA[b + 2], sA[b + 3]);
                u32 a2 = cvt_pk_bf16(sA[b + 4], sA[b + 5]);
                u32 a3 = cvt_pk_bf16(sA[b + 6], sA[b + 7]);
                asm("v_permlane32_swap_b32 %0, %1" : "+v"(a0), "+v"(a2));
                asm("v_permlane32_swap_b32 %0, %1" : "+v"(a1), "+v"(a3));
                union { u32 u[4]; bf16x8 v; } ua;
                ua.u[0] = a0; ua.u[1] = a1; ua.u[2] = a2; ua.u[3] = a3;
                pfA[kbl] = ua.v;
                u32 b0 = cvt_pk_bf16(sB[b + 0], sB[b + 1]);
                u32 b1 = cvt_pk_bf16(sB[b + 2], sB[b + 3]);
                u32 b2 = cvt_pk_bf16(sB[b + 4], sB[b + 5]);
                u32 b3 = cvt_pk_bf16(sB[b + 6], sB[b + 7]);
                asm("v_permlane32_swap_b32 %0, %1" : "+v"(b0), "+v"(b2));
                asm("v_permlane32_swap_b32 %0, %1" : "+v"(b1), "+v"(b3));
                union { u32 u[4]; bf16x8 v; } ub;
                ub.u[0] = b0; ub.u[1] = b1; ub.u[2] = b2; ub.u[3] = b3;
                pfB[kbl] = ub.v;
            }

            __builtin_amdgcn_s_setprio(1);
            #pragma unroll
            for (int kbl = 0; kbl < 2; ++kbl) {
                const int jcc = jb * 4 + 2 * kbl + h;
                #pragma unroll
                for (int cb = 0; cb < 4; ++cb) {
                    bf16x8 vf = *(const bf16x8*)(Vlds + jcc * 2048 + (cb * 32 + l31) * 16);
                    accA[cb] = __builtin_amdgcn_mfma_f32_32x32x16_bf16(vf, pfA[kbl], accA[cb], 0, 0, 0);
                    accB[cb] = __builtin_amdgcn_mfma_f32_32x32x16_bf16(vf, pfB[kbl], accB[cb], 0, 0, 0);
                }
            }
            __builtin_amdgcn_s_setprio(0);
        }
    };

    // ---- T4 pipeline: counted vmcnt, loads in flight across barriers ----
    // WAITBAR(N): wait until <=N of this wave's loads outstanding, then align.
    #define WAITBAR(N) do { \
        asm volatile("s_waitcnt vmcnt(" #N ")" ::: "memory"); \
        __builtin_amdgcn_s_barrier(); \
        __builtin_amdgcn_sched_barrier(0); \
    } while (0)
    // BAR(): read-done fence before overwriting a buffer (no vmcnt drain).
    #define BAR() do { \
        __builtin_amdgcn_sched_barrier(0); \
        __builtin_amdgcn_s_barrier(); \
        __builtin_amdgcn_sched_barrier(0); \
    } while (0)

    stage(0, jt0);
    int t = 0;
    for (; t + 2 <= NT; t += 2) {
        stage(1, jt0 + t + 1);       // 6 new loads; previous 6 ahead of them
        WAITBAR(6);                  // buf0 (tile t) resident everywhere
        compute(0);
        BAR();                       // all waves done reading buf0
        if (t + 2 < NT) {
            stage(0, jt0 + t + 2);
            WAITBAR(6);              // buf1 (tile t+1) resident
        } else {
            WAITBAR(0);              // last pair: drain buf1's loads
        }
        compute(1);
        BAR();                       // all waves done reading buf1
    }
    if (t < NT) {                    // odd NT tail: tile t staged in last pair
        asm volatile("s_waitcnt vmcnt(0)" ::: "memory");
        __builtin_amdgcn_s_barrier();
        __builtin_amdgcn_sched_barrier(0);
        compute(0);
    }
    #undef WAITBAR
    #undef BAR

    lsA += __shfl_xor(lsA, 32, 64);
    lsB += __shfl_xor(lsB, 32, 64);

    // epilogue (identical to R5): q = l31 lane-local; c = cb*32+(r&3)+8(r>>2)+4h
    if (Opart != nullptr) {
        float* Ob = Opart + (size_t)(js * 4 + n) * 128 * HW;
        #pragma unroll
        for (int cb = 0; cb < 4; ++cb)
            #pragma unroll
            for (int r = 0; r < 16; ++r) {
                int c = cb * 32 + (r & 3) + 8 * (r >> 2) + 4 * h;
                Ob[(size_t)c * HW + rowA] = accA[cb][r];
                Ob[(size_t)c * HW + rowB] = accB[cb][r];
            }
        if (h == 0) {
            Mpart[(size_t)(js * 4 + n) * HW + rowA] = mA;
            Mpart[(size_t)(js * 4 + n) * HW + rowB] = mB;
            Lpart[(size_t)(js * 4 + n) * HW + rowA] = lsA;
            Lpart[(size_t)(js * 4 + n) * HW + rowB] = lsB;
        }
    } else {
        float invA = 1.f / lsA, invB = 1.f / lsB;
        float* ob = out + (size_t)n * 128 * HW;
        #pragma unroll
        for (int cb = 0; cb < 4; ++cb)
            #pragma unroll
            for (int r = 0; r < 16; ++r) {
                int c = cb * 32 + (r & 3) + 8 * (r >> 2) + 4 * h;
                ob[(size_t)c * HW + rowA] = accA[cb][r] * invA;
                ob[(size_t)c * HW + rowB] = accB[cb][r] * invB;
            }
    }
}

// ---------------- Combine (M-aware, jsplit <= 5) ----------------
__global__ __launch_bounds__(256) void combine_kernel(
    const float* __restrict__ Opart, const float* __restrict__ Mpart,
    const float* __restrict__ Lpart, float* __restrict__ out, int jsplit)
{
    const int b = blockIdx.x;
    const int n = b / 100;
    const int rem = b - n * 100;
    const int cq = rem / 25;
    const int ic = rem - cq * 25;
    const int i = ic * 256 + threadIdx.x;

    float mj[5], wj[5];
    float M = -3e38f;
    #pragma unroll
    for (int js = 0; js < 5; ++js) {
        mj[js] = (js < jsplit) ? Mpart[(size_t)(js * 4 + n) * HW + i] : -3e38f;
        M = fmaxf(M, mj[js]);
    }
    float L = 0.f;
    #pragma unroll
    for (int js = 0; js < 5; ++js) {
        wj[js] = (js < jsplit) ? exp2f(mj[js] - M) : 0.f;
        if (js < jsplit) L += Lpart[(size_t)(js * 4 + n) * HW + i] * wj[js];
    }
    const float inv = 1.f / L;

    for (int c = cq * 32; c < cq * 32 + 32; ++c) {
        float acc = 0.f;
        #pragma unroll
        for (int js = 0; js < 5; ++js)
            if (js < jsplit)
                acc += Opart[((size_t)(js * 4 + n) * 128 + c) * HW + i] * wj[js];
        out[((size_t)n * 128 + c) * HW + i] = acc * inv;
    }
}

extern "C" void kernel_launch(void* const* d_in, const int* in_sizes, int n_in,
                              void* d_out, int out_size, void* d_ws, size_t ws_size,
                              hipStream_t stream) {
    const float* x  = (const float*)d_in[0];
    const float* Wq = (const float*)d_in[1];
    const float* bq = (const float*)d_in[2];
    const float* aq = (const float*)d_in[3];
    const float* Wk = (const float*)d_in[4];
    const float* bk = (const float*)d_in[5];
    const float* ak = (const float*)d_in[6];
    const float* Wv = (const float*)d_in[7];
    const float* bv = (const float*)d_in[8];
    const float* av = (const float*)d_in[9];

    char* wsp = (char*)d_ws;
    u16* QT  = (u16*)wsp;                          // [4][6400][64] bf16 p-major = 3,276,800 B
    u16* KT  = (u16*)(wsp + 3276800);              // [4][6400][64] bf16 p-major = 3,276,800 B
    u16* Vw  = (u16*)(wsp + 6553600);              // [4][128][6400] bf16 c-major = 6,553,600 B
    const size_t base = 13107200;
    const size_t oslab = 13107200;                 // 4n x 128 x HW x 4B per js
    const size_t mslab = 102400;                   // 4n x HW x 4B

    proj_kernel<<<dim3(400), 256, 0, stream>>>(x, Wq, bq, aq, Wk, bk, ak, Wv, bv, av,
                                               QT, KT, Vw);

    int jsplit = 0;
    for (int js = 5; js >= 4; --js) {
        size_t need = base + (size_t)js * (oslab + 2 * mslab);
        if (ws_size >= need) { jsplit = js; break; }
    }

    if (jsplit > 0) {
        float* Opart = (float*)(wsp + base);
        float* Mpart = (float*)(wsp + base + (size_t)jsplit * oslab);
        float* Lpart = (float*)(wsp + base + (size_t)jsplit * (oslab + mslab));
        int NT = 100 / jsplit;
        attn_kernel<<<dim3(4 * 25 * jsplit), 256, 0, stream>>>(QT, KT, Vw, (float*)d_out,
                                                               Opart, Mpart, Lpart, jsplit, NT);
        combine_kernel<<<dim3(400), 256, 0, stream>>>(Opart, Mpart, Lpart, (float*)d_out, jsplit);
    } else {
        attn_kernel<<<dim3(100), 256, 0, stream>>>(QT, KT, Vw, (float*)d_out,
                                                   nullptr, nullptr, nullptr, 1, 100);
    }
}

// Round 10
// 167.041 us; speedup vs baseline: 1.2561x; 1.0875x over previous
//
#include <hip/hip_runtime.h>

typedef __attribute__((ext_vector_type(8)))  short bf16x8;
typedef __attribute__((ext_vector_type(16))) float f32x16;
typedef unsigned int u32;
typedef unsigned short u16;

#define HW 6400
#define L2E 1.44269504088896f
#define DEFER_THR 8.0f

__device__ inline u16 f2bf(float f) {
    u32 u = __builtin_bit_cast(u32, f);
    u32 r = (u + 0x7fffu + ((u >> 16) & 1u)) >> 16;
    return (u16)r;
}
__device__ inline u32 cvt_pk_bf16(float lo, float hi) {
    u32 r;
    asm("v_cvt_pk_bf16_f32 %0, %1, %2" : "=v"(r) : "v"(lo), "v"(hi));
    return r;
}
__device__ inline void gload_lds16(const void* g, void* l) {
    __builtin_amdgcn_global_load_lds(
        (const __attribute__((address_space(1))) u32*)g,
        (__attribute__((address_space(3))) u32*)l, 16, 0, 0);
}
// depth-4 tree max over 16 lane-local values
__device__ inline float vmax16(const f32x16& v) {
    float a0 = fmaxf(v[0], v[1]),  a1 = fmaxf(v[2], v[3]);
    float a2 = fmaxf(v[4], v[5]),  a3 = fmaxf(v[6], v[7]);
    float a4 = fmaxf(v[8], v[9]),  a5 = fmaxf(v[10], v[11]);
    float a6 = fmaxf(v[12], v[13]), a7 = fmaxf(v[14], v[15]);
    float b0 = fmaxf(a0, a1), b1 = fmaxf(a2, a3);
    float b2 = fmaxf(a4, a5), b3 = fmaxf(a6, a7);
    return fmaxf(fmaxf(b0, b1), fmaxf(b2, b3));
}
// sum of the two bf16 values packed in w (bitcasts are free)
__device__ inline float bfpair_sum(u32 w) {
    float hi = __builtin_bit_cast(float, w & 0xFFFF0000u);
    float lo = __builtin_bit_cast(float, w << 16);
    return hi + lo;
}

// ---------------- Projection kernel (bf16 MFMA — R7/R8-proven, verbatim) ----------------
__global__ __launch_bounds__(256) void proj_kernel(
    const float* __restrict__ x,
    const float* __restrict__ Wq, const float* __restrict__ bq, const float* __restrict__ aq,
    const float* __restrict__ Wk, const float* __restrict__ bk, const float* __restrict__ ak,
    const float* __restrict__ Wv, const float* __restrict__ bv, const float* __restrict__ av,
    u16* __restrict__ QT, u16* __restrict__ KT, u16* __restrict__ Vw)
{
    __shared__ char xs[64 * 272];
    __shared__ char ktr[2][64 * 144];

    const int tid  = threadIdx.x;
    const int lane = tid & 63;
    const int w    = tid >> 6;
    const int l31  = lane & 31;
    const int h    = lane >> 5;

    const int blk = blockIdx.x;
    const int n   = blk / 100;
    const int pt  = blk - n * 100;
    const int p0  = pt * 64;

    const float* xb = x + (size_t)n * 128 * HW + p0;
    #pragma unroll
    for (int it = 0; it < 8; ++it) {
        int idx = it * 256 + tid;
        int c = idx >> 4, p4 = (idx & 15) * 4;
        float4 d = *(const float4*)(xb + (size_t)c * HW + p4);
        *(u16*)(xs + (p4 + 0) * 272 + c * 2) = f2bf(d.x);
        *(u16*)(xs + (p4 + 1) * 272 + c * 2) = f2bf(d.y);
        *(u16*)(xs + (p4 + 2) * 272 + c * 2) = f2bf(d.z);
        *(u16*)(xs + (p4 + 3) * 272 + c * 2) = f2bf(d.w);
    }
    __syncthreads();

    const float* Wsrc; const float* bsrc; float slope; float osc = 1.0f;
    if (w == 0)      { Wsrc = Wq;                 bsrc = bq;             slope = aq[0]; osc = L2E; }
    else if (w == 1) { Wsrc = Wk;                 bsrc = bk;             slope = ak[0]; }
    else             { Wsrc = Wv + (w-2)*64*128;  bsrc = bv + (w-2)*64;  slope = av[0]; }

    bf16x8 wf[2][8];
    #pragma unroll
    for (int cb = 0; cb < 2; ++cb)
        #pragma unroll
        for (int kc = 0; kc < 8; ++kc) {
            const float* ws = Wsrc + (cb * 32 + l31) * 128 + kc * 16 + h * 8;
            float4 a = *(const float4*)ws;
            float4 b = *(const float4*)(ws + 4);
            union { u32 u[4]; bf16x8 v; } uu;
            uu.u[0] = cvt_pk_bf16(a.x, a.y);
            uu.u[1] = cvt_pk_bf16(a.z, a.w);
            uu.u[2] = cvt_pk_bf16(b.x, b.y);
            uu.u[3] = cvt_pk_bf16(b.z, b.w);
            wf[cb][kc] = uu.v;
        }

    f32x16 acc[2][2] = {};
    #pragma unroll
    for (int kc = 0; kc < 8; ++kc) {
        bf16x8 xb0 = *(const bf16x8*)(xs + (l31)      * 272 + kc * 32 + h * 16);
        bf16x8 xb1 = *(const bf16x8*)(xs + (l31 + 32) * 272 + kc * 32 + h * 16);
        acc[0][0] = __builtin_amdgcn_mfma_f32_32x32x16_bf16(wf[0][kc], xb0, acc[0][0], 0, 0, 0);
        acc[0][1] = __builtin_amdgcn_mfma_f32_32x32x16_bf16(wf[0][kc], xb1, acc[0][1], 0, 0, 0);
        acc[1][0] = __builtin_amdgcn_mfma_f32_32x32x16_bf16(wf[1][kc], xb0, acc[1][0], 0, 0, 0);
        acc[1][1] = __builtin_amdgcn_mfma_f32_32x32x16_bf16(wf[1][kc], xb1, acc[1][1], 0, 0, 0);
    }

    if (w >= 2) {
        u16* dst = Vw + ((size_t)n * 128 + (size_t)(w - 2) * 64) * HW;
        #pragma unroll
        for (int cb = 0; cb < 2; ++cb)
            #pragma unroll
            for (int pb = 0; pb < 2; ++pb)
                #pragma unroll
                for (int r = 0; r < 16; ++r) {
                    int ch = cb * 32 + (r & 3) + 8 * (r >> 2) + 4 * h;
                    float y = acc[cb][pb][r] + bsrc[ch];
                    y = (y >= 0.f) ? y : slope * y;
                    dst[(size_t)ch * HW + p0 + pb * 32 + l31] = f2bf(y);
                }
    } else {
        char* tb = ktr[w];
        #pragma unroll
        for (int cb = 0; cb < 2; ++cb)
            #pragma unroll
            for (int pb = 0; pb < 2; ++pb)
                #pragma unroll
                for (int rp = 0; rp < 8; ++rp) {
                    int r0 = rp * 2;
                    int ch = cb * 32 + (r0 & 3) + 8 * (r0 >> 2) + 4 * h;
                    float y0 = acc[cb][pb][r0]     + bsrc[ch];
                    float y1 = acc[cb][pb][r0 + 1] + bsrc[ch + 1];
                    y0 = ((y0 >= 0.f) ? y0 : slope * y0) * osc;
                    y1 = ((y1 >= 0.f) ? y1 : slope * y1) * osc;
                    *(u32*)(tb + (pb * 32 + l31) * 144 + ch * 2) = cvt_pk_bf16(y0, y1);
                }
        u16* dst = (w == 0) ? QT : KT;
        #pragma unroll
        for (int i8 = 0; i8 < 8; ++i8) {
            int p = i8 * 8 + (lane >> 3);
            bf16x8 d = *(const bf16x8*)(tb + p * 144 + (lane & 7) * 16);
            *(bf16x8*)(dst + ((size_t)n * HW + p0 + p) * 64 + (lane & 7) * 8) = d;
        }
    }
}

// ---------------- Flash attention (R8 fences restored + lean VALU) ----------------
// block 256 = 4 waves x 64 q-rows (dual-set A/B); grid = 4n x 25 it x jsplit.
// Fence structure IDENTICAL to R8 (rule #18: sched_barrier(0) after inline-asm
// waitcnt/barrier is a correctness fence). Deltas vs R8: tree row-max,
// decoupled per-set rescale (THR=8), row-sums from bf16-ROUNDED packed P
// (numerator/denominator consistency -> more absmax headroom).
__global__ __launch_bounds__(256, 2) void attn_kernel(
    const u16* __restrict__ QT, const u16* __restrict__ KT, const u16* __restrict__ Vw,
    float* __restrict__ out,
    float* __restrict__ Opart, float* __restrict__ Mpart, float* __restrict__ Lpart,
    int jsplit, int NT)
{
    __shared__ char lds[49152];        // 2 x (K 8KB + V 16KB)

    const int tid  = threadIdx.x;
    const int lane = tid & 63;
    const int w    = tid >> 6;
    const int l31  = lane & 31;
    const int h    = lane >> 5;

    const int per_n = 25 * jsplit;
    const int n    = blockIdx.x / per_n;
    const int rem  = blockIdx.x - n * per_n;
    const int it   = rem / jsplit;
    const int js   = rem - it * jsplit;
    const int i0   = it * 256;
    const int jt0  = js * NT;

    const int rowA = i0 + w * 64 + l31;
    const int rowB = rowA + 32;

    const u16* qbA = QT + ((size_t)n * HW + rowA) * 64;
    bf16x8 qfA[4], qfB[4];
    #pragma unroll
    for (int kc = 0; kc < 4; ++kc) {
        qfA[kc] = *(const bf16x8*)(qbA + kc * 16 + h * 8);
        qfB[kc] = *(const bf16x8*)(qbA + 32 * 64 + kc * 16 + h * 8);
    }

    const char* Kg = (const char*)(KT + (size_t)n * HW * 64);    // [p][64] bf16, 128B rows
    const char* Vg = (const char*)(Vw + (size_t)n * 128 * HW);   // [c][HW] bf16

    auto stage = [&](int buf, int jt) {
        char* B = lds + buf * 24576;
        #pragma unroll
        for (int q = 0; q < 2; ++q) {
            int cc = w + 4 * q;
            gload_lds16(Kg + (size_t)jt * 8192 + lane * 128 + cc * 16, B + cc * 1024);
        }
        #pragma unroll
        for (int q = 0; q < 4; ++q) {
            int v = w + 4 * q;
            int jcc = v >> 1, chalf = v & 1;
            gload_lds16(Vg + (size_t)(chalf * 64 + lane) * 12800 + (size_t)jt * 128 + jcc * 16,
                        B + 8192 + v * 1024);
        }
    };

    f32x16 accA[4] = {}, accB[4] = {};
    float mA = -3e38f, mB = -3e38f, lsA = 0.f, lsB = 0.f;

    auto compute = [&](int buf) {
        char* Klds = lds + buf * 24576;
        char* Vlds = Klds + 8192;

        #pragma unroll
        for (int jb = 0; jb < 2; ++jb) {
            bf16x8 kf[4];
            #pragma unroll
            for (int kc = 0; kc < 4; ++kc)
                kf[kc] = *(const bf16x8*)(Klds + (2 * kc + h) * 1024 + (jb * 32 + l31) * 16);

            __builtin_amdgcn_s_setprio(1);
            f32x16 sA = {}, sB = {};
            #pragma unroll
            for (int kc = 0; kc < 4; ++kc) {
                sA = __builtin_amdgcn_mfma_f32_32x32x16_bf16(kf[kc], qfA[kc], sA, 0, 0, 0);
                sB = __builtin_amdgcn_mfma_f32_32x32x16_bf16(kf[kc], qfB[kc], sB, 0, 0, 0);
            }
            __builtin_amdgcn_s_setprio(0);

            // tree row-max + cross-half merge
            float rmxA = vmax16(sA), rmxB = vmax16(sB);
            rmxA = fmaxf(rmxA, __shfl_xor(rmxA, 32, 64));
            rmxB = fmaxf(rmxB, __shfl_xor(rmxB, 32, 64));

            // decoupled defer-max rescales
            if (__any(rmxA > mA + DEFER_THR)) {
                float mn = fmaxf(mA, rmxA);
                float a = exp2f(mA - mn);
                lsA *= a;
                #pragma unroll
                for (int cb = 0; cb < 4; ++cb)
                    #pragma unroll
                    for (int r = 0; r < 16; ++r) accA[cb][r] *= a;
                mA = mn;
            }
            if (__any(rmxB > mB + DEFER_THR)) {
                float mn = fmaxf(mB, rmxB);
                float a = exp2f(mB - mn);
                lsB *= a;
                #pragma unroll
                for (int cb = 0; cb < 4; ++cb)
                    #pragma unroll
                    for (int r = 0; r < 16; ++r) accB[cb][r] *= a;
                mB = mn;
            }

            #pragma unroll
            for (int r = 0; r < 16; ++r) {
                sA[r] = exp2f(sA[r] - mA);
                sB[r] = exp2f(sB[r] - mB);
            }

            // pack P^T B-frags; row-sums from the ROUNDED packed words
            float rsA = 0.f, rsB = 0.f;
            bf16x8 pfA[2], pfB[2];
            #pragma unroll
            for (int kbl = 0; kbl < 2; ++kbl) {
                const int b = kbl * 8;
                u32 a0 = cvt_pk_bf16(sA[b + 0], sA[b + 1]);
                u32 a1 = cvt_pk_bf16(sA[b + 2], sA[b + 3]);
                u32 a2 = cvt_pk_bf16(sA[b + 4], sA[b + 5]);
                u32 a3 = cvt_pk_bf16(sA[b + 6], sA[b + 7]);
                rsA += (bfpair_sum(a0) + bfpair_sum(a1)) + (bfpair_sum(a2) + bfpair_sum(a3));
                asm("v_permlane32_swap_b32 %0, %1" : "+v"(a0), "+v"(a2));
                asm("v_permlane32_swap_b32 %0, %1" : "+v"(a1), "+v"(a3));
                union { u32 u[4]; bf16x8 v; } ua;
                ua.u[0] = a0; ua.u[1] = a1; ua.u[2] = a2; ua.u[3] = a3;
                pfA[kbl] = ua.v;
                u32 b0 = cvt_pk_bf16(sB[b + 0], sB[b + 1]);
                u32 b1 = cvt_pk_bf16(sB[b + 2], sB[b + 3]);
                u32 b2 = cvt_pk_bf16(sB[b + 4], sB[b + 5]);
                u32 b3 = cvt_pk_bf16(sB[b + 6], sB[b + 7]);
                rsB += (bfpair_sum(b0) + bfpair_sum(b1)) + (bfpair_sum(b2) + bfpair_sum(b3));
                asm("v_permlane32_swap_b32 %0, %1" : "+v"(b0), "+v"(b2));
                asm("v_permlane32_swap_b32 %0, %1" : "+v"(b1), "+v"(b3));
                union { u32 u[4]; bf16x8 v; } ub;
                ub.u[0] = b0; ub.u[1] = b1; ub.u[2] = b2; ub.u[3] = b3;
                pfB[kbl] = ub.v;
            }
            lsA += rsA;
            lsB += rsB;

            __builtin_amdgcn_s_setprio(1);
            #pragma unroll
            for (int kbl = 0; kbl < 2; ++kbl) {
                const int jcc = jb * 4 + 2 * kbl + h;
                #pragma unroll
                for (int cb = 0; cb < 4; ++cb) {
                    bf16x8 vf = *(const bf16x8*)(Vlds + jcc * 2048 + (cb * 32 + l31) * 16);
                    accA[cb] = __builtin_amdgcn_mfma_f32_32x32x16_bf16(vf, pfA[kbl], accA[cb], 0, 0, 0);
                    accB[cb] = __builtin_amdgcn_mfma_f32_32x32x16_bf16(vf, pfB[kbl], accB[cb], 0, 0, 0);
                }
            }
            __builtin_amdgcn_s_setprio(0);
        }
    };

    // ---- T4 pipeline with R8's EXACT fence structure (rule #18 pins) ----
    #define WAITBAR(N) do { \
        asm volatile("s_waitcnt vmcnt(" #N ")" ::: "memory"); \
        __builtin_amdgcn_s_barrier(); \
        __builtin_amdgcn_sched_barrier(0); \
    } while (0)
    #define BAR() do { \
        __builtin_amdgcn_sched_barrier(0); \
        __builtin_amdgcn_s_barrier(); \
        __builtin_amdgcn_sched_barrier(0); \
    } while (0)

    stage(0, jt0);
    int t = 0;
    for (; t + 2 <= NT; t += 2) {
        stage(1, jt0 + t + 1);
        WAITBAR(6);
        compute(0);
        BAR();
        if (t + 2 < NT) {
            stage(0, jt0 + t + 2);
            WAITBAR(6);
        } else {
            WAITBAR(0);
        }
        compute(1);
        BAR();
    }
    if (t < NT) {
        asm volatile("s_waitcnt vmcnt(0)" ::: "memory");
        __builtin_amdgcn_s_barrier();
        __builtin_amdgcn_sched_barrier(0);
        compute(0);
    }
    #undef WAITBAR
    #undef BAR

    lsA += __shfl_xor(lsA, 32, 64);
    lsB += __shfl_xor(lsB, 32, 64);

    if (Opart != nullptr) {
        float* Ob = Opart + (size_t)(js * 4 + n) * 128 * HW;
        #pragma unroll
        for (int cb = 0; cb < 4; ++cb)
            #pragma unroll
            for (int r = 0; r < 16; ++r) {
                int c = cb * 32 + (r & 3) + 8 * (r >> 2) + 4 * h;
                Ob[(size_t)c * HW + rowA] = accA[cb][r];
                Ob[(size_t)c * HW + rowB] = accB[cb][r];
            }
        if (h == 0) {
            Mpart[(size_t)(js * 4 + n) * HW + rowA] = mA;
            Mpart[(size_t)(js * 4 + n) * HW + rowB] = mB;
            Lpart[(size_t)(js * 4 + n) * HW + rowA] = lsA;
            Lpart[(size_t)(js * 4 + n) * HW + rowB] = lsB;
        }
    } else {
        float invA = 1.f / lsA, invB = 1.f / lsB;
        float* ob = out + (size_t)n * 128 * HW;
        #pragma unroll
        for (int cb = 0; cb < 4; ++cb)
            #pragma unroll
            for (int r = 0; r < 16; ++r) {
                int c = cb * 32 + (r & 3) + 8 * (r >> 2) + 4 * h;
                ob[(size_t)c * HW + rowA] = accA[cb][r] * invA;
                ob[(size_t)c * HW + rowB] = accB[cb][r] * invB;
            }
    }
}

// ---------------- Combine (M-aware, jsplit <= 5) ----------------
__global__ __launch_bounds__(256) void combine_kernel(
    const float* __restrict__ Opart, const float* __restrict__ Mpart,
    const float* __restrict__ Lpart, float* __restrict__ out, int jsplit)
{
    const int b = blockIdx.x;
    const int n = b / 100;
    const int rem = b - n * 100;
    const int cq = rem / 25;
    const int ic = rem - cq * 25;
    const int i = ic * 256 + threadIdx.x;

    float mj[5], wj[5];
    float M = -3e38f;
    #pragma unroll
    for (int js = 0; js < 5; ++js) {
        mj[js] = (js < jsplit) ? Mpart[(size_t)(js * 4 + n) * HW + i] : -3e38f;
        M = fmaxf(M, mj[js]);
    }
    float L = 0.f;
    #pragma unroll
    for (int js = 0; js < 5; ++js) {
        wj[js] = (js < jsplit) ? exp2f(mj[js] - M) : 0.f;
        if (js < jsplit) L += Lpart[(size_t)(js * 4 + n) * HW + i] * wj[js];
    }
    const float inv = 1.f / L;

    for (int c = cq * 32; c < cq * 32 + 32; ++c) {
        float acc = 0.f;
        #pragma unroll
        for (int js = 0; js < 5; ++js)
            if (js < jsplit)
                acc += Opart[((size_t)(js * 4 + n) * 128 + c) * HW + i] * wj[js];
        out[((size_t)n * 128 + c) * HW + i] = acc * inv;
    }
}

extern "C" void kernel_launch(void* const* d_in, const int* in_sizes, int n_in,
                              void* d_out, int out_size, void* d_ws, size_t ws_size,
                              hipStream_t stream) {
    const float* x  = (const float*)d_in[0];
    const float* Wq = (const float*)d_in[1];
    const float* bq = (const float*)d_in[2];
    const float* aq = (const float*)d_in[3];
    const float* Wk = (const float*)d_in[4];
    const float* bk = (const float*)d_in[5];
    const float* ak = (const float*)d_in[6];
    const float* Wv = (const float*)d_in[7];
    const float* bv = (const float*)d_in[8];
    const float* av = (const float*)d_in[9];

    char* wsp = (char*)d_ws;
    u16* QT  = (u16*)wsp;                          // [4][6400][64] bf16 p-major = 3,276,800 B
    u16* KT  = (u16*)(wsp + 3276800);              // [4][6400][64] bf16 p-major = 3,276,800 B
    u16* Vw  = (u16*)(wsp + 6553600);              // [4][128][6400] bf16 c-major = 6,553,600 B
    const size_t base = 13107200;
    const size_t oslab = 13107200;                 // 4n x 128 x HW x 4B per js
    const size_t mslab = 102400;                   // 4n x HW x 4B

    proj_kernel<<<dim3(400), 256, 0, stream>>>(x, Wq, bq, aq, Wk, bk, ak, Wv, bv, av,
                                               QT, KT, Vw);

    int jsplit = 0;
    for (int js = 5; js >= 4; --js) {
        size_t need = base + (size_t)js * (oslab + 2 * mslab);
        if (ws_size >= need) { jsplit = js; break; }
    }

    if (jsplit > 0) {
        float* Opart = (float*)(wsp + base);
        float* Mpart = (float*)(wsp + base + (size_t)jsplit * oslab);
        float* Lpart = (float*)(wsp + base + (size_t)jsplit * (oslab + mslab));
        int NT = 100 / jsplit;
        attn_kernel<<<dim3(4 * 25 * jsplit), 256, 0, stream>>>(QT, KT, Vw, (float*)d_out,
                                                               Opart, Mpart, Lpart, jsplit, NT);
        combine_kernel<<<dim3(400), 256, 0, stream>>>(Opart, Mpart, Lpart, (float*)d_out, jsplit);
    } else {
        attn_kernel<<<dim3(100), 256, 0, stream>>>(QT, KT, Vw, (float*)d_out,
                                                   nullptr, nullptr, nullptr, 1, 100);
    }
}

// Round 11
// 143.714 us; speedup vs baseline: 1.4600x; 1.1623x over previous
//
#include <hip/hip_runtime.h>

typedef __attribute__((ext_vector_type(8)))  short bf16x8;
typedef __attribute__((ext_vector_type(16))) float f32x16;
typedef unsigned int u32;
typedef unsigned short u16;

#define HW 6400
#define L2E 1.44269504088896f
#define DEFER_THR 8.0f
#define XPITCH 260   // 65 dwords -> bank step 1 per p-row (conflict-free)
#define KPITCH 132   // 33 dwords -> bank step 1 per p-row

__device__ inline u16 f2bf(float f) {
    u32 u = __builtin_bit_cast(u32, f);
    u32 r = (u + 0x7fffu + ((u >> 16) & 1u)) >> 16;
    return (u16)r;
}
__device__ inline u32 cvt_pk_bf16(float lo, float hi) {
    u32 r;
    asm("v_cvt_pk_bf16_f32 %0, %1, %2" : "=v"(r) : "v"(lo), "v"(hi));
    return r;
}
__device__ inline void gload_lds16(const void* g, void* l) {
    __builtin_amdgcn_global_load_lds(
        (const __attribute__((address_space(1))) u32*)g,
        (__attribute__((address_space(3))) u32*)l, 16, 0, 0);
}
// depth-4 tree max / sum over 16 lane-local values
__device__ inline float vmax16(const f32x16& v) {
    float a0 = fmaxf(v[0], v[1]),  a1 = fmaxf(v[2], v[3]);
    float a2 = fmaxf(v[4], v[5]),  a3 = fmaxf(v[6], v[7]);
    float a4 = fmaxf(v[8], v[9]),  a5 = fmaxf(v[10], v[11]);
    float a6 = fmaxf(v[12], v[13]), a7 = fmaxf(v[14], v[15]);
    float b0 = fmaxf(a0, a1), b1 = fmaxf(a2, a3);
    float b2 = fmaxf(a4, a5), b3 = fmaxf(a6, a7);
    return fmaxf(fmaxf(b0, b1), fmaxf(b2, b3));
}
__device__ inline float vsum16(const f32x16& v) {
    float a0 = v[0] + v[1],  a1 = v[2] + v[3];
    float a2 = v[4] + v[5],  a3 = v[6] + v[7];
    float a4 = v[8] + v[9],  a5 = v[10] + v[11];
    float a6 = v[12] + v[13], a7 = v[14] + v[15];
    float b0 = a0 + a1, b1 = a2 + a3, b2 = a4 + a5, b3 = a6 + a7;
    return (b0 + b1) + (b2 + b3);
}

// ---------------- Projection kernel (bf16 MFMA; conflict-free LDS pitches) ----------------
// wave 0 -> Q (x log2e, p-major via LDS transpose), wave 1 -> K (p-major via
// LDS transpose), waves 2/3 -> V[0:64]/V[64:128] (bf16 c-major).
__global__ __launch_bounds__(256) void proj_kernel(
    const float* __restrict__ x,
    const float* __restrict__ Wq, const float* __restrict__ bq, const float* __restrict__ aq,
    const float* __restrict__ Wk, const float* __restrict__ bk, const float* __restrict__ ak,
    const float* __restrict__ Wv, const float* __restrict__ bv, const float* __restrict__ av,
    u16* __restrict__ QT, u16* __restrict__ KT, u16* __restrict__ Vw)
{
    __shared__ char xs[64 * XPITCH];       // [64 p][128 ch bf16], pitch 260B
    __shared__ char ktr[2][64 * KPITCH];   // Q/K transpose buffers, pitch 132B

    const int tid  = threadIdx.x;
    const int lane = tid & 63;
    const int w    = tid >> 6;
    const int l31  = lane & 31;
    const int h    = lane >> 5;

    const int blk = blockIdx.x;
    const int n   = blk / 100;
    const int pt  = blk - n * 100;
    const int p0  = pt * 64;

    const float* xb = x + (size_t)n * 128 * HW + p0;
    #pragma unroll
    for (int it = 0; it < 8; ++it) {
        int idx = it * 256 + tid;
        int c = idx >> 4, p4 = (idx & 15) * 4;
        float4 d = *(const float4*)(xb + (size_t)c * HW + p4);
        *(u16*)(xs + (p4 + 0) * XPITCH + c * 2) = f2bf(d.x);
        *(u16*)(xs + (p4 + 1) * XPITCH + c * 2) = f2bf(d.y);
        *(u16*)(xs + (p4 + 2) * XPITCH + c * 2) = f2bf(d.z);
        *(u16*)(xs + (p4 + 3) * XPITCH + c * 2) = f2bf(d.w);
    }
    __syncthreads();

    const float* Wsrc; const float* bsrc; float slope; float osc = 1.0f;
    if (w == 0)      { Wsrc = Wq;                 bsrc = bq;             slope = aq[0]; osc = L2E; }
    else if (w == 1) { Wsrc = Wk;                 bsrc = bk;             slope = ak[0]; }
    else             { Wsrc = Wv + (w-2)*64*128;  bsrc = bv + (w-2)*64;  slope = av[0]; }

    bf16x8 wf[2][8];
    #pragma unroll
    for (int cb = 0; cb < 2; ++cb)
        #pragma unroll
        for (int kc = 0; kc < 8; ++kc) {
            const float* ws = Wsrc + (cb * 32 + l31) * 128 + kc * 16 + h * 8;
            float4 a = *(const float4*)ws;
            float4 b = *(const float4*)(ws + 4);
            union { u32 u[4]; bf16x8 v; } uu;
            uu.u[0] = cvt_pk_bf16(a.x, a.y);
            uu.u[1] = cvt_pk_bf16(a.z, a.w);
            uu.u[2] = cvt_pk_bf16(b.x, b.y);
            uu.u[3] = cvt_pk_bf16(b.z, b.w);
            wf[cb][kc] = uu.v;
        }

    f32x16 acc[2][2] = {};
    #pragma unroll
    for (int kc = 0; kc < 8; ++kc) {
        bf16x8 xb0 = *(const bf16x8*)(xs + (l31)      * XPITCH + kc * 32 + h * 16);
        bf16x8 xb1 = *(const bf16x8*)(xs + (l31 + 32) * XPITCH + kc * 32 + h * 16);
        acc[0][0] = __builtin_amdgcn_mfma_f32_32x32x16_bf16(wf[0][kc], xb0, acc[0][0], 0, 0, 0);
        acc[0][1] = __builtin_amdgcn_mfma_f32_32x32x16_bf16(wf[0][kc], xb1, acc[0][1], 0, 0, 0);
        acc[1][0] = __builtin_amdgcn_mfma_f32_32x32x16_bf16(wf[1][kc], xb0, acc[1][0], 0, 0, 0);
        acc[1][1] = __builtin_amdgcn_mfma_f32_32x32x16_bf16(wf[1][kc], xb1, acc[1][1], 0, 0, 0);
    }

    if (w >= 2) {
        u16* dst = Vw + ((size_t)n * 128 + (size_t)(w - 2) * 64) * HW;
        #pragma unroll
        for (int cb = 0; cb < 2; ++cb)
            #pragma unroll
            for (int pb = 0; pb < 2; ++pb)
                #pragma unroll
                for (int r = 0; r < 16; ++r) {
                    int ch = cb * 32 + (r & 3) + 8 * (r >> 2) + 4 * h;
                    float y = acc[cb][pb][r] + bsrc[ch];
                    y = (y >= 0.f) ? y : slope * y;
                    dst[(size_t)ch * HW + p0 + pb * 32 + l31] = f2bf(y);
                }
    } else {
        char* tb = ktr[w];
        #pragma unroll
        for (int cb = 0; cb < 2; ++cb)
            #pragma unroll
            for (int pb = 0; pb < 2; ++pb)
                #pragma unroll
                for (int rp = 0; rp < 8; ++rp) {
                    int r0 = rp * 2;
                    int ch = cb * 32 + (r0 & 3) + 8 * (r0 >> 2) + 4 * h;
                    float y0 = acc[cb][pb][r0]     + bsrc[ch];
                    float y1 = acc[cb][pb][r0 + 1] + bsrc[ch + 1];
                    y0 = ((y0 >= 0.f) ? y0 : slope * y0) * osc;
                    y1 = ((y1 >= 0.f) ? y1 : slope * y1) * osc;
                    *(u32*)(tb + (pb * 32 + l31) * KPITCH + ch * 2) = cvt_pk_bf16(y0, y1);
                }
        u16* dst = (w == 0) ? QT : KT;
        #pragma unroll
        for (int i8 = 0; i8 < 8; ++i8) {
            int p = i8 * 8 + (lane >> 3);
            bf16x8 d = *(const bf16x8*)(tb + p * KPITCH + (lane & 7) * 16);
            *(bf16x8*)(dst + ((size_t)n * HW + p0 + p) * 64 + (lane & 7) * 8) = d;
        }
    }
}

// ---------------- Flash attention (R10 structure; raw exp2 + vsum16 diet) ----------------
// block 256 = 4 waves x 64 q-rows (dual-set A/B); grid = 4n x 25 it x jsplit.
// Fence structure IDENTICAL to R8/R10 (rule #18 sched_barrier(0) pins).
__global__ __launch_bounds__(256, 2) void attn_kernel(
    const u16* __restrict__ QT, const u16* __restrict__ KT, const u16* __restrict__ Vw,
    float* __restrict__ out,
    float* __restrict__ Opart, float* __restrict__ Mpart, float* __restrict__ Lpart,
    int jsplit, int NT)
{
    __shared__ char lds[49152];        // 2 x (K 8KB + V 16KB)

    const int tid  = threadIdx.x;
    const int lane = tid & 63;
    const int w    = tid >> 6;
    const int l31  = lane & 31;
    const int h    = lane >> 5;

    const int per_n = 25 * jsplit;
    const int n    = blockIdx.x / per_n;
    const int rem  = blockIdx.x - n * per_n;
    const int it   = rem / jsplit;
    const int js   = rem - it * jsplit;
    const int i0   = it * 256;
    const int jt0  = js * NT;

    const int rowA = i0 + w * 64 + l31;
    const int rowB = rowA + 32;

    const u16* qbA = QT + ((size_t)n * HW + rowA) * 64;
    bf16x8 qfA[4], qfB[4];
    #pragma unroll
    for (int kc = 0; kc < 4; ++kc) {
        qfA[kc] = *(const bf16x8*)(qbA + kc * 16 + h * 8);
        qfB[kc] = *(const bf16x8*)(qbA + 32 * 64 + kc * 16 + h * 8);
    }

    const char* Kg = (const char*)(KT + (size_t)n * HW * 64);    // [p][64] bf16, 128B rows
    const char* Vg = (const char*)(Vw + (size_t)n * 128 * HW);   // [c][HW] bf16

    auto stage = [&](int buf, int jt) {
        char* B = lds + buf * 24576;
        #pragma unroll
        for (int q = 0; q < 2; ++q) {
            int cc = w + 4 * q;
            gload_lds16(Kg + (size_t)jt * 8192 + lane * 128 + cc * 16, B + cc * 1024);
        }
        #pragma unroll
        for (int q = 0; q < 4; ++q) {
            int v = w + 4 * q;
            int jcc = v >> 1, chalf = v & 1;
            gload_lds16(Vg + (size_t)(chalf * 64 + lane) * 12800 + (size_t)jt * 128 + jcc * 16,
                        B + 8192 + v * 1024);
        }
    };

    f32x16 accA[4] = {}, accB[4] = {};
    float mA = -3e38f, mB = -3e38f, lsA = 0.f, lsB = 0.f;

    auto compute = [&](int buf) {
        char* Klds = lds + buf * 24576;
        char* Vlds = Klds + 8192;

        #pragma unroll
        for (int jb = 0; jb < 2; ++jb) {
            bf16x8 kf[4];
            #pragma unroll
            for (int kc = 0; kc < 4; ++kc)
                kf[kc] = *(const bf16x8*)(Klds + (2 * kc + h) * 1024 + (jb * 32 + l31) * 16);

            __builtin_amdgcn_s_setprio(1);
            f32x16 sA = {}, sB = {};
            #pragma unroll
            for (int kc = 0; kc < 4; ++kc) {
                sA = __builtin_amdgcn_mfma_f32_32x32x16_bf16(kf[kc], qfA[kc], sA, 0, 0, 0);
                sB = __builtin_amdgcn_mfma_f32_32x32x16_bf16(kf[kc], qfB[kc], sB, 0, 0, 0);
            }
            __builtin_amdgcn_s_setprio(0);

            // tree row-max + cross-half merge
            float rmxA = vmax16(sA), rmxB = vmax16(sB);
            rmxA = fmaxf(rmxA, __shfl_xor(rmxA, 32, 64));
            rmxB = fmaxf(rmxB, __shfl_xor(rmxB, 32, 64));

            // decoupled defer-max rescales (raw exp2: args <= +8 by defer bound)
            if (__any(rmxA > mA + DEFER_THR)) {
                float mn = fmaxf(mA, rmxA);
                float a = __builtin_amdgcn_exp2f(mA - mn);
                lsA *= a;
                #pragma unroll
                for (int cb = 0; cb < 4; ++cb)
                    #pragma unroll
                    for (int r = 0; r < 16; ++r) accA[cb][r] *= a;
                mA = mn;
            }
            if (__any(rmxB > mB + DEFER_THR)) {
                float mn = fmaxf(mB, rmxB);
                float a = __builtin_amdgcn_exp2f(mB - mn);
                lsB *= a;
                #pragma unroll
                for (int cb = 0; cb < 4; ++cb)
                    #pragma unroll
                    for (int r = 0; r < 16; ++r) accB[cb][r] *= a;
                mB = mn;
            }

            #pragma unroll
            for (int r = 0; r < 16; ++r) {
                sA[r] = __builtin_amdgcn_exp2f(sA[r] - mA);
                sB[r] = __builtin_amdgcn_exp2f(sB[r] - mB);
            }
            lsA += vsum16(sA);
            lsB += vsum16(sB);

            bf16x8 pfA[2], pfB[2];
            #pragma unroll
            for (int kbl = 0; kbl < 2; ++kbl) {
                const int b = kbl * 8;
                u32 a0 = cvt_pk_bf16(sA[b + 0], sA[b + 1]);
                u32 a1 = cvt_pk_bf16(sA[b + 2], sA[b + 3]);
                u32 a2 = cvt_pk_bf16(sA[b + 4], sA[b + 5]);
                u32 a3 = cvt_pk_bf16(sA[b + 6], sA[b + 7]);
                asm("v_permlane32_swap_b32 %0, %1" : "+v"(a0), "+v"(a2));
                asm("v_permlane32_swap_b32 %0, %1" : "+v"(a1), "+v"(a3));
                union { u32 u[4]; bf16x8 v; } ua;
                ua.u[0] = a0; ua.u[1] = a1; ua.u[2] = a2; ua.u[3] = a3;
                pfA[kbl] = ua.v;
                u32 b0 = cvt_pk_bf16(sB[b + 0], sB[b + 1]);
                u32 b1 = cvt_pk_bf16(sB[b + 2], sB[b + 3]);
                u32 b2 = cvt_pk_bf16(sB[b + 4], sB[b + 5]);
                u32 b3 = cvt_pk_bf16(sB[b + 6], sB[b + 7]);
                asm("v_permlane32_swap_b32 %0, %1" : "+v"(b0), "+v"(b2));
                asm("v_permlane32_swap_b32 %0, %1" : "+v"(b1), "+v"(b3));
                union { u32 u[4]; bf16x8 v; } ub;
                ub.u[0] = b0; ub.u[1] = b1; ub.u[2] = b2; ub.u[3] = b3;
                pfB[kbl] = ub.v;
            }

            __builtin_amdgcn_s_setprio(1);
            #pragma unroll
            for (int kbl = 0; kbl < 2; ++kbl) {
                const int jcc = jb * 4 + 2 * kbl + h;
                #pragma unroll
                for (int cb = 0; cb < 4; ++cb) {
                    bf16x8 vf = *(const bf16x8*)(Vlds + jcc * 2048 + (cb * 32 + l31) * 16);
                    accA[cb] = __builtin_amdgcn_mfma_f32_32x32x16_bf16(vf, pfA[kbl], accA[cb], 0, 0, 0);
                    accB[cb] = __builtin_amdgcn_mfma_f32_32x32x16_bf16(vf, pfB[kbl], accB[cb], 0, 0, 0);
                }
            }
            __builtin_amdgcn_s_setprio(0);
        }
    };

    // ---- T4 pipeline with R8's EXACT fence structure (rule #18 pins) ----
    #define WAITBAR(N) do { \
        asm volatile("s_waitcnt vmcnt(" #N ")" ::: "memory"); \
        __builtin_amdgcn_s_barrier(); \
        __builtin_amdgcn_sched_barrier(0); \
    } while (0)
    #define BAR() do { \
        __builtin_amdgcn_sched_barrier(0); \
        __builtin_amdgcn_s_barrier(); \
        __builtin_amdgcn_sched_barrier(0); \
    } while (0)

    stage(0, jt0);
    int t = 0;
    for (; t + 2 <= NT; t += 2) {
        stage(1, jt0 + t + 1);
        WAITBAR(6);
        compute(0);
        BAR();
        if (t + 2 < NT) {
            stage(0, jt0 + t + 2);
            WAITBAR(6);
        } else {
            WAITBAR(0);
        }
        compute(1);
        BAR();
    }
    if (t < NT) {
        asm volatile("s_waitcnt vmcnt(0)" ::: "memory");
        __builtin_amdgcn_s_barrier();
        __builtin_amdgcn_sched_barrier(0);
        compute(0);
    }
    #undef WAITBAR
    #undef BAR

    lsA += __shfl_xor(lsA, 32, 64);
    lsB += __shfl_xor(lsB, 32, 64);

    if (Opart != nullptr) {
        float* Ob = Opart + (size_t)(js * 4 + n) * 128 * HW;
        #pragma unroll
        for (int cb = 0; cb < 4; ++cb)
            #pragma unroll
            for (int r = 0; r < 16; ++r) {
                int c = cb * 32 + (r & 3) + 8 * (r >> 2) + 4 * h;
                Ob[(size_t)c * HW + rowA] = accA[cb][r];
                Ob[(size_t)c * HW + rowB] = accB[cb][r];
            }
        if (h == 0) {
            Mpart[(size_t)(js * 4 + n) * HW + rowA] = mA;
            Mpart[(size_t)(js * 4 + n) * HW + rowB] = mB;
            Lpart[(size_t)(js * 4 + n) * HW + rowA] = lsA;
            Lpart[(size_t)(js * 4 + n) * HW + rowB] = lsB;
        }
    } else {
        float invA = 1.f / lsA, invB = 1.f / lsB;
        float* ob = out + (size_t)n * 128 * HW;
        #pragma unroll
        for (int cb = 0; cb < 4; ++cb)
            #pragma unroll
            for (int r = 0; r < 16; ++r) {
                int c = cb * 32 + (r & 3) + 8 * (r >> 2) + 4 * h;
                ob[(size_t)c * HW + rowA] = accA[cb][r] * invA;
                ob[(size_t)c * HW + rowB] = accB[cb][r] * invB;
            }
    }
}

// ---------------- Combine (M-aware, jsplit <= 5) ----------------
__global__ __launch_bounds__(256) void combine_kernel(
    const float* __restrict__ Opart, const float* __restrict__ Mpart,
    const float* __restrict__ Lpart, float* __restrict__ out, int jsplit)
{
    const int b = blockIdx.x;
    const int n = b / 100;
    const int rem = b - n * 100;
    const int cq = rem / 25;
    const int ic = rem - cq * 25;
    const int i = ic * 256 + threadIdx.x;

    float mj[5], wj[5];
    float M = -3e38f;
    #pragma unroll
    for (int js = 0; js < 5; ++js) {
        mj[js] = (js < jsplit) ? Mpart[(size_t)(js * 4 + n) * HW + i] : -3e38f;
        M = fmaxf(M, mj[js]);
    }
    float L = 0.f;
    #pragma unroll
    for (int js = 0; js < 5; ++js) {
        wj[js] = (js < jsplit) ? __builtin_amdgcn_exp2f(mj[js] - M) : 0.f;
        if (js < jsplit) L += Lpart[(size_t)(js * 4 + n) * HW + i] * wj[js];
    }
    const float inv = 1.f / L;

    for (int c = cq * 32; c < cq * 32 + 32; ++c) {
        float acc = 0.f;
        #pragma unroll
        for (int js = 0; js < 5; ++js)
            if (js < jsplit)
                acc += Opart[((size_t)(js * 4 + n) * 128 + c) * HW + i] * wj[js];
        out[((size_t)n * 128 + c) * HW + i] = acc * inv;
    }
}

extern "C" void kernel_launch(void* const* d_in, const int* in_sizes, int n_in,
                              void* d_out, int out_size, void* d_ws, size_t ws_size,
                              hipStream_t stream) {
    const float* x  = (const float*)d_in[0];
    const float* Wq = (const float*)d_in[1];
    const float* bq = (const float*)d_in[2];
    const float* aq = (const float*)d_in[3];
    const float* Wk = (const float*)d_in[4];
    const float* bk = (const float*)d_in[5];
    const float* ak = (const float*)d_in[6];
    const float* Wv = (const float*)d_in[7];
    const float* bv = (const float*)d_in[8];
    const float* av = (const float*)d_in[9];

    char* wsp = (char*)d_ws;
    u16* QT  = (u16*)wsp;                          // [4][6400][64] bf16 p-major = 3,276,800 B
    u16* KT  = (u16*)(wsp + 3276800);              // [4][6400][64] bf16 p-major = 3,276,800 B
    u16* Vw  = (u16*)(wsp + 6553600);              // [4][128][6400] bf16 c-major = 6,553,600 B
    const size_t base = 13107200;
    const size_t oslab = 13107200;                 // 4n x 128 x HW x 4B per js
    const size_t mslab = 102400;                   // 4n x HW x 4B

    proj_kernel<<<dim3(400), 256, 0, stream>>>(x, Wq, bq, aq, Wk, bk, ak, Wv, bv, av,
                                               QT, KT, Vw);

    int jsplit = 0;
    for (int js = 5; js >= 4; --js) {
        size_t need = base + (size_t)js * (oslab + 2 * mslab);
        if (ws_size >= need) { jsplit = js; break; }
    }

    if (jsplit > 0) {
        float* Opart = (float*)(wsp + base);
        float* Mpart = (float*)(wsp + base + (size_t)jsplit * oslab);
        float* Lpart = (float*)(wsp + base + (size_t)jsplit * (oslab + mslab));
        int NT = 100 / jsplit;
        attn_kernel<<<dim3(4 * 25 * jsplit), 256, 0, stream>>>(QT, KT, Vw, (float*)d_out,
                                                               Opart, Mpart, Lpart, jsplit, NT);
        combine_kernel<<<dim3(400), 256, 0, stream>>>(Opart, Mpart, Lpart, (float*)d_out, jsplit);
    } else {
        attn_kernel<<<dim3(100), 256, 0, stream>>>(QT, KT, Vw, (float*)d_out,
                                                   nullptr, nullptr, nullptr, 1, 100);
    }
}